// Round 10
// baseline (394.248 us; speedup 1.0000x reference)
//
#include <hip/hip_runtime.h>

#define DD 1024
#define NN 256
#define BB 64
#define EE 16
#define SS 16
#define HH 256
#define ES 256
#define BN 16384

typedef unsigned short u16;
typedef unsigned int u32;
typedef __attribute__((ext_vector_type(8))) short bf16x8;
typedef __attribute__((ext_vector_type(4))) float f32x4;

#define MFMA(a, b, c) __builtin_amdgcn_mfma_f32_16x16x32_bf16(a, b, c, 0, 0, 0)

__device__ __forceinline__ u16 f2b(float f) {
  union { float f; u32 i; } c; c.f = f;
  u32 i = c.i;
  u32 r = (i + 0x7FFFu + ((i >> 16) & 1u)) >> 16;
  return (u16)r;
}

// block = 256 threads (4 waves). Sums v across the block, result broadcast.
__device__ __forceinline__ float bredsum(float v, float* red) {
  #pragma unroll
  for (int o = 32; o > 0; o >>= 1) v += __shfl_down(v, o, 64);
  __syncthreads();
  if ((threadIdx.x & 63) == 0) red[threadIdx.x >> 6] = v;
  __syncthreads();
  return red[0] + red[1] + red[2] + red[3];
}

// ---------------- K1: per-token LN stats + l2 factor ----------------
__global__ __launch_bounds__(256) void k_stats(
    const float* __restrict__ x, const float* __restrict__ gamma,
    const float* __restrict__ beta, const float* __restrict__ scale,
    float* __restrict__ mean_, float* __restrict__ rstd_,
    float* __restrict__ fct_) {
  __shared__ float red[4];
  int bn = blockIdx.x, t = threadIdx.x;
  float4 u = ((const float4*)(x + (size_t)bn * DD))[t];
  float s = u.x + u.y + u.z + u.w;
  float ss = u.x * u.x + u.y * u.y + u.z * u.z + u.w * u.w;
  s = bredsum(s, red);
  ss = bredsum(ss, red);
  float mean = s * (1.0f / DD);
  float var = ss * (1.0f / DD) - mean * mean;
  float rstd = rsqrtf(var + 1e-5f);
  float4 g = ((const float4*)gamma)[t];
  float4 be = ((const float4*)beta)[t];
  float x0 = (u.x - mean) * rstd * g.x + be.x;
  float x1 = (u.y - mean) * rstd * g.y + be.y;
  float x2 = (u.z - mean) * rstd * g.z + be.z;
  float x3 = (u.w - mean) * rstd * g.w + be.w;
  float s2 = x0 * x0 + x1 * x1 + x2 * x2 + x3 * x3;
  s2 = bredsum(s2, red);
  float f = scale[0] / fmaxf(sqrtf(s2), 1e-12f);
  if (t == 0) { mean_[bn] = mean; rstd_[bn] = rstd; fct_[bn] = f; }
}

// ------- K2: rmun[es] = 1/max(||mu[:,es]||,eps); c3 = rmun*sum(g*mu); c4 = rmun*sum(be*mu)
__global__ __launch_bounds__(256) void k_rmun(
    const float* __restrict__ mu, const float* __restrict__ gamma,
    const float* __restrict__ beta, float* __restrict__ rmun,
    float* __restrict__ c3, float* __restrict__ c4) {
  __shared__ float red[4];
  int es = blockIdx.x, t = threadIdx.x;
  float ss = 0.f, s3 = 0.f, s4 = 0.f;
  #pragma unroll
  for (int j = 0; j < 4; j++) {
    int d = t + j * 256;
    float v = mu[(size_t)d * ES + es];
    ss += v * v;
    s3 += gamma[d] * v;
    s4 += beta[d] * v;
  }
  ss = bredsum(ss, red);
  s3 = bredsum(s3, red);
  s4 = bredsum(s4, red);
  if (t == 0) {
    float r = 1.0f / fmaxf(sqrtf(ss), 1e-12f);
    rmun[es] = r;
    c3[es] = s3 * r;
    c4[es] = s4 * r;
  }
}

// ------- K3: muT[es][d] = mu[d][es]*rmun[es]*gamma[d] (bf16, K-major) -------
__global__ __launch_bounds__(256) void k_mut(
    const float* __restrict__ mu, const float* __restrict__ gamma,
    const float* __restrict__ rmun, u16* __restrict__ muT) {
  __shared__ u16 L[256 * 70];
  int t = threadIdx.x;
  int d0 = blockIdx.x * 64;
  float rm = rmun[t];
  for (int i = 0; i < 64; i++) {
    int d = d0 + i;
    float gv = gamma[d];
    L[t * 70 + i] = f2b(mu[(size_t)d * ES + t] * rm * gv);
  }
  __syncthreads();
  u32 buf[32];
  #pragma unroll
  for (int k2 = 0; k2 < 32; k2++)
    buf[k2] = *(const u32*)&L[t * 70 + k2 * 2];
  u16* dst = muT + (size_t)t * DD + d0;
  #pragma unroll
  for (int k4 = 0; k4 < 8; k4++) {
    uint4 o;
    o.x = buf[k4 * 4]; o.y = buf[k4 * 4 + 1];
    o.z = buf[k4 * 4 + 2]; o.w = buf[k4 * 4 + 3];
    *(uint4*)(dst + k4 * 8) = o;
  }
}

// ------- K4: xT[d][bn] = bf16(x[bn][d]) — raw-x transpose -------
__global__ __launch_bounds__(256) void k_xt(
    const float* __restrict__ x, u16* __restrict__ xT) {
  __shared__ u16 L[256 * 70];
  int t = threadIdx.x;
  int bn0 = blockIdx.x * 64;
  for (int cch = 0; cch < 4; cch++) {
    __syncthreads();
    for (int r = 0; r < 64; r++)
      L[t * 70 + r] = f2b(x[(size_t)(bn0 + r) * DD + cch * 256 + t]);
    __syncthreads();
    u32 buf[32];
    #pragma unroll
    for (int k2 = 0; k2 < 32; k2++)
      buf[k2] = *(const u32*)&L[t * 70 + k2 * 2];
    u16* dst = xT + (size_t)(cch * 256 + t) * BN + bn0;
    #pragma unroll
    for (int k4 = 0; k4 < 8; k4++) {
      uint4 o;
      o.x = buf[k4 * 4]; o.y = buf[k4 * 4 + 1];
      o.z = buf[k4 * 4 + 2]; o.w = buf[k4 * 4 + 3];
      *(uint4*)(dst + k4 * 8) = o;
    }
  }
}

// ------- K5: generic per-expert transpose: src[e][R][C] fp32 -> dst[e][C][R] bf16
__global__ __launch_bounds__(256) void k_tr(
    const float* __restrict__ src, u16* __restrict__ dst, int R, int C) {
  __shared__ u16 T[64 * 70];
  int t = threadIdx.x;
  int e = blockIdx.y;
  int tR = R >> 6;
  int r0 = (blockIdx.x % tR) * 64;
  int c0 = (blockIdx.x / tR) * 64;
  #pragma unroll
  for (int i = 0; i < 16; i++) {
    int r = r0 + i * 4 + (t >> 6);
    int c = t & 63;
    T[c * 70 + i * 4 + (t >> 6)] = f2b(src[((size_t)e * R + r) * C + c0 + c]);
  }
  __syncthreads();
  int cl = t >> 2, rsg = (t & 3) * 16;
  u32 buf[8];
  #pragma unroll
  for (int k2 = 0; k2 < 8; k2++)
    buf[k2] = *(const u32*)&T[cl * 70 + rsg + k2 * 2];
  u16* dp = dst + ((size_t)e * C + c0 + cl) * R + r0 + rsg;
  uint4 o0, o1;
  o0.x = buf[0]; o0.y = buf[1]; o0.z = buf[2]; o0.w = buf[3];
  o1.x = buf[4]; o1.y = buf[5]; o1.z = buf[6]; o1.w = buf[7];
  *(uint4*)dp = o0;
  *(uint4*)(dp + 8) = o1;
}

// ------- K6: logitsT[es][bn] via MFMA: fct*(rs*(X.MU') - rs*mn*c3 + c4) -------
// 16-token strips: grid 1024 (4 blocks/CU, 16 waves/CU) — was 256 (1/CU,
// 9% occupancy, latency-bound). Wave w owns es strip w*64; reg-prefetch.
__global__ __launch_bounds__(256) void k_logits_mfma(
    const float* __restrict__ x, const u16* __restrict__ muT,
    const float* __restrict__ mean_, const float* __restrict__ rstd_,
    const float* __restrict__ fct_, const float* __restrict__ c3,
    const float* __restrict__ c4, float* __restrict__ logitsT) {
  __shared__ u16 xb[16 * 136];  // [16 bn][128 k] bf16, K-major, pad 8
  int t = threadIdx.x;
  int lane = t & 63, w = t >> 6, q = lane >> 4, m16 = lane & 15;
  int bn0 = blockIdx.x * 16;
  int es0 = w * 64;
  f32x4 z = {0.f, 0.f, 0.f, 0.f};
  f32x4 acc[4];
  #pragma unroll
  for (int mt = 0; mt < 4; mt++) acc[mt] = z;
  int sr = t >> 4, cc = (t & 15) * 8;  // row 0..15, 8-float col chunk
  const float* xrow = x + (size_t)(bn0 + sr) * DD + cc;
  float4 pf0 = *(const float4*)(xrow);
  float4 pf1 = *(const float4*)(xrow + 4);
  for (int kb = 0; kb < 8; kb++) {
    __syncthreads();
    {
      uint4 pk;
      pk.x = (u32)f2b(pf0.x) | ((u32)f2b(pf0.y) << 16);
      pk.y = (u32)f2b(pf0.z) | ((u32)f2b(pf0.w) << 16);
      pk.z = (u32)f2b(pf1.x) | ((u32)f2b(pf1.y) << 16);
      pk.w = (u32)f2b(pf1.z) | ((u32)f2b(pf1.w) << 16);
      *(uint4*)&xb[sr * 136 + cc] = pk;
    }
    __syncthreads();
    if (kb < 7) {
      pf0 = *(const float4*)(xrow + (kb + 1) * 128);
      pf1 = *(const float4*)(xrow + (kb + 1) * 128 + 4);
    }
    #pragma unroll
    for (int ks = 0; ks < 4; ks++) {
      int k = ks * 32 + q * 8;
      bf16x8 bb = *(const bf16x8*)&xb[m16 * 136 + k];
      #pragma unroll
      for (int mt = 0; mt < 4; mt++) {
        bf16x8 a = *(const bf16x8*)(muT + (size_t)(es0 + mt * 16 + m16) * DD +
                                    kb * 128 + k);
        acc[mt] = MFMA(a, bb, acc[mt]);
      }
    }
  }
  int bn = bn0 + m16;
  float fv = fct_[bn], rv = rstd_[bn], mv = mean_[bn];
  #pragma unroll
  for (int mt = 0; mt < 4; mt++)
    #pragma unroll
    for (int i = 0; i < 4; i++) {
      int es = es0 + mt * 16 + q * 4 + i;
      float val = fv * (rv * acc[mt][i] - rv * mv * c3[es] + c4[es]);
      logitsT[(size_t)es * BN + bn] = val;
    }
}

// ------- K6b: dispatch softmax -> dispW[b][es][n] bf16 (K-major n) + c1g[b][es]
__global__ __launch_bounds__(256) void k_disp(
    const float* __restrict__ logitsT, const float* __restrict__ mean_,
    const float* __restrict__ rstd_, u16* __restrict__ dispW,
    float* __restrict__ c1g) {
  int t = threadIdx.x;
  int e = blockIdx.x, b = blockIdx.y;
  int s = t >> 4, c = t & 15;
  const float* lrow = logitsT + (size_t)(e * 16 + s) * BN + b * 256 + c * 16;
  float lv[16];
  #pragma unroll
  for (int i2 = 0; i2 < 4; i2++) {
    float4 f = *(const float4*)(lrow + i2 * 4);
    lv[i2 * 4 + 0] = f.x; lv[i2 * 4 + 1] = f.y;
    lv[i2 * 4 + 2] = f.z; lv[i2 * 4 + 3] = f.w;
  }
  float mx = -1e30f;
  #pragma unroll
  for (int i = 0; i < 16; i++) mx = fmaxf(mx, lv[i]);
  #pragma unroll
  for (int o = 1; o < 16; o <<= 1) mx = fmaxf(mx, __shfl_xor(mx, o, 64));
  float sum = 0.f;
  #pragma unroll
  for (int i = 0; i < 16; i++) { lv[i] = __expf(lv[i] - mx); sum += lv[i]; }
  #pragma unroll
  for (int o = 1; o < 16; o <<= 1) sum += __shfl_xor(sum, o, 64);
  float inv = 1.0f / sum;
  float c1p = 0.f;
  u16 wp[16];
  #pragma unroll
  for (int i = 0; i < 16; i++) {
    int n = c * 16 + i;
    float wv = lv[i] * inv * rstd_[b * 256 + n];
    c1p += wv * mean_[b * 256 + n];
    wp[i] = f2b(wv);
  }
  #pragma unroll
  for (int o = 1; o < 16; o <<= 1) c1p += __shfl_xor(c1p, o, 64);
  if (c == 0) c1g[(b << 8) + e * 16 + s] = c1p;
  u16* drow = dispW + ((size_t)(b * 256 + e * 16 + s)) * 256 + c * 16;
  #pragma unroll
  for (int i2 = 0; i2 < 4; i2++) {
    uint2 pk;
    pk.x = (u32)wp[i2 * 4] | ((u32)wp[i2 * 4 + 1] << 16);
    pk.y = (u32)wp[i2 * 4 + 2] | ((u32)wp[i2 * 4 + 3] << 16);
    *(uint2*)(drow + i2 * 4) = pk;
  }
}

// ------- K6c: in-place combine-softmax normalization of logitsT -------
__global__ __launch_bounds__(256) void k_comb(float* __restrict__ logitsT) {
  __shared__ float red[4][64];
  int t = threadIdx.x;
  int l = t & 63, g = t >> 6;
  int bn = blockIdx.y * 256 + blockIdx.x * 64 + l;
  float* base = logitsT + (size_t)(g * 64) * BN + bn;
  float ev[64];
  float sum = 0.f;
  #pragma unroll
  for (int i = 0; i < 64; i++) {
    float e = __expf(base[(size_t)i * BN]);
    ev[i] = e;
    sum += e;
  }
  red[g][l] = sum;
  __syncthreads();
  float inv = 1.0f / (red[0][l] + red[1][l] + red[2][l] + red[3][l]);
  #pragma unroll
  for (int i = 0; i < 64; i++)
    base[(size_t)i * BN] = ev[i] * inv;
}

// ------- K7a: SI[e][b*16+s][d] = gamma*(dispW[b] @ xT - c1) + beta  (M=256) ----
__global__ __launch_bounds__(256) void k_slotin(
    const u16* __restrict__ xT, const u16* __restrict__ dispW,
    const float* __restrict__ c1g, const float* __restrict__ gamma,
    const float* __restrict__ beta, u16* __restrict__ SI) {
  __shared__ u16 xb[128 * 264];  // [128 d][256 n] pad->264 (2-way bank = free)
  int t = threadIdx.x;
  int lane = t & 63, w = t >> 6, q = lane >> 4, m16 = lane & 15;
  int d0 = blockIdx.x * 128, b = blockIdx.y;
  #pragma unroll
  for (int it = 0; it < 16; it++) {
    int c = it * 256 + t;
    int row = c >> 5, off = (c & 31) * 8;
    uint4 v = *(const uint4*)(xT + (size_t)(d0 + row) * BN + b * 256 + off);
    *(uint4*)&xb[row * 264 + off] = v;
  }
  __syncthreads();
  f32x4 z = {0.f, 0.f, 0.f, 0.f};
  f32x4 acc[4][8];
  #pragma unroll
  for (int mt = 0; mt < 4; mt++)
    #pragma unroll
    for (int nt = 0; nt < 8; nt++) acc[mt][nt] = z;
  int es0 = w * 64;
  for (int ks = 0; ks < 8; ks++) {
    int k = ks * 32 + q * 8;
    bf16x8 a[4];
    #pragma unroll
    for (int mt = 0; mt < 4; mt++)
      a[mt] = *(const bf16x8*)(dispW +
               ((size_t)(b * 256 + es0 + mt * 16 + m16)) * 256 + k);
    #pragma unroll
    for (int nt = 0; nt < 8; nt++) {
      bf16x8 bb = *(const bf16x8*)&xb[(nt * 16 + m16) * 264 + k];
      #pragma unroll
      for (int mt = 0; mt < 4; mt++) acc[mt][nt] = MFMA(a[mt], bb, acc[mt][nt]);
    }
  }
  float gv[8], bev[8];
  #pragma unroll
  for (int nt = 0; nt < 8; nt++) {
    int d = d0 + nt * 16 + m16;
    gv[nt] = gamma[d]; bev[nt] = beta[d];
  }
  #pragma unroll
  for (int mt = 0; mt < 4; mt++) {
    float c1[4];
    #pragma unroll
    for (int i = 0; i < 4; i++)
      c1[i] = c1g[(b << 8) + es0 + mt * 16 + q * 4 + i];
    #pragma unroll
    for (int nt = 0; nt < 8; nt++)
      #pragma unroll
      for (int i = 0; i < 4; i++)
        SI[((size_t)(w * 4 + mt) * 1024 + b * 16 + q * 4 + i) * DD + d0 +
           nt * 16 + m16] = f2b(gv[nt] * (acc[mt][nt][i] - c1[i]) + bev[nt]);
  }
}

// ------- K7b1: H[e][bs][h] = gelu(SI @ w1T + b1); tile 64x64, K=1024 -------
__global__ __launch_bounds__(256) void k_mlp1(
    const u16* __restrict__ SI, const u16* __restrict__ w1T,
    const float* __restrict__ b1, u16* __restrict__ H) {
  __shared__ u16 At[64 * 72];
  __shared__ u16 Bt[64 * 72];
  int t = threadIdx.x;
  int lane = t & 63, w = t >> 6, q = lane >> 4, m16 = lane & 15;
  int nt0 = blockIdx.x * 64;   // h
  int mt0 = blockIdx.y * 64;   // bs
  int e = blockIdx.z;
  int wm = (w & 1) * 32, wn = (w >> 1) * 32;
  f32x4 z = {0.f, 0.f, 0.f, 0.f};
  f32x4 acc[2][2];
  #pragma unroll
  for (int mt = 0; mt < 2; mt++)
    #pragma unroll
    for (int nt = 0; nt < 2; nt++) acc[mt][nt] = z;
  const u16* Ab = SI + ((size_t)e * 1024 + mt0) * DD;
  const u16* Bb = w1T + ((size_t)e * HH + nt0) * DD;
  int row = t >> 2, off = (t & 3) * 16;
  uint4 pa0, pa1, pb0, pb1;
  pa0 = *(const uint4*)(Ab + (size_t)row * DD + off);
  pa1 = *(const uint4*)(Ab + (size_t)row * DD + off + 8);
  pb0 = *(const uint4*)(Bb + (size_t)row * DD + off);
  pb1 = *(const uint4*)(Bb + (size_t)row * DD + off + 8);
  for (int kb = 0; kb < 16; kb++) {
    *(uint4*)&At[row * 72 + off] = pa0;
    *(uint4*)&At[row * 72 + off + 8] = pa1;
    *(uint4*)&Bt[row * 72 + off] = pb0;
    *(uint4*)&Bt[row * 72 + off + 8] = pb1;
    __syncthreads();
    if (kb < 15) {
      int k0 = (kb + 1) * 64;
      pa0 = *(const uint4*)(Ab + (size_t)row * DD + k0 + off);
      pa1 = *(const uint4*)(Ab + (size_t)row * DD + k0 + off + 8);
      pb0 = *(const uint4*)(Bb + (size_t)row * DD + k0 + off);
      pb1 = *(const uint4*)(Bb + (size_t)row * DD + k0 + off + 8);
    }
    #pragma unroll
    for (int kk = 0; kk < 2; kk++) {
      int k = kk * 32 + q * 8;
      bf16x8 a[2], bb[2];
      #pragma unroll
      for (int mt = 0; mt < 2; mt++)
        a[mt] = *(const bf16x8*)&At[(wm + mt * 16 + m16) * 72 + k];
      #pragma unroll
      for (int nt = 0; nt < 2; nt++)
        bb[nt] = *(const bf16x8*)&Bt[(wn + nt * 16 + m16) * 72 + k];
      #pragma unroll
      for (int mt = 0; mt < 2; mt++)
        #pragma unroll
        for (int nt = 0; nt < 2; nt++)
          acc[mt][nt] = MFMA(a[mt], bb[nt], acc[mt][nt]);
    }
    __syncthreads();
  }
  #pragma unroll
  for (int nt = 0; nt < 2; nt++) {
    int h = nt0 + wn + nt * 16 + m16;
    float b1v = b1[e * HH + h];
    #pragma unroll
    for (int mt = 0; mt < 2; mt++)
      #pragma unroll
      for (int i = 0; i < 4; i++) {
        float zz = acc[mt][nt][i] + b1v;
        int bs = mt0 + wm + mt * 16 + q * 4 + i;
        H[((size_t)e * 1024 + bs) * HH + h] =
            f2b(0.5f * zz * (1.0f + erff(zz * 0.70710678118654752f)));
      }
  }
}

// ------- K7b2: SO[e][bs][d] = H @ w2T + b2; tile 64x64, K=256 -------
// k_mlp1 recipe: 4096 blocks (8/CU by LDS), reg-prefetch staging; epilogue
// goes through LDS (At reused) for full-line coalesced uint4 stores.
__global__ __launch_bounds__(256) void k_mlp2(
    const u16* __restrict__ H, const u16* __restrict__ w2T,
    const float* __restrict__ b2, u16* __restrict__ SO) {
  __shared__ u16 At[64 * 72];
  __shared__ u16 Bt[64 * 72];
  int t = threadIdx.x;
  int lane = t & 63, w = t >> 6, q = lane >> 4, m16 = lane & 15;
  int nt0 = blockIdx.x * 64;   // d
  int mt0 = blockIdx.y * 64;   // bs
  int e = blockIdx.z;
  int wm = (w & 1) * 32, wn = (w >> 1) * 32;
  f32x4 z = {0.f, 0.f, 0.f, 0.f};
  f32x4 acc[2][2];
  #pragma unroll
  for (int mt = 0; mt < 2; mt++)
    #pragma unroll
    for (int nt = 0; nt < 2; nt++) acc[mt][nt] = z;
  const u16* Ab = H + ((size_t)e * 1024 + mt0) * HH;
  const u16* Bb = w2T + ((size_t)e * DD + nt0) * HH;
  int row = t >> 2, off = (t & 3) * 16;
  uint4 pa0, pa1, pb0, pb1;
  pa0 = *(const uint4*)(Ab + (size_t)row * HH + off);
  pa1 = *(const uint4*)(Ab + (size_t)row * HH + off + 8);
  pb0 = *(const uint4*)(Bb + (size_t)row * HH + off);
  pb1 = *(const uint4*)(Bb + (size_t)row * HH + off + 8);
  for (int kb = 0; kb < 4; kb++) {
    *(uint4*)&At[row * 72 + off] = pa0;
    *(uint4*)&At[row * 72 + off + 8] = pa1;
    *(uint4*)&Bt[row * 72 + off] = pb0;
    *(uint4*)&Bt[row * 72 + off + 8] = pb1;
    __syncthreads();
    if (kb < 3) {
      int k0 = (kb + 1) * 64;
      pa0 = *(const uint4*)(Ab + (size_t)row * HH + k0 + off);
      pa1 = *(const uint4*)(Ab + (size_t)row * HH + k0 + off + 8);
      pb0 = *(const uint4*)(Bb + (size_t)row * HH + k0 + off);
      pb1 = *(const uint4*)(Bb + (size_t)row * HH + k0 + off + 8);
    }
    #pragma unroll
    for (int kk = 0; kk < 2; kk++) {
      int k = kk * 32 + q * 8;
      bf16x8 a[2], bb[2];
      #pragma unroll
      for (int mt = 0; mt < 2; mt++)
        a[mt] = *(const bf16x8*)&At[(wm + mt * 16 + m16) * 72 + k];
      #pragma unroll
      for (int nt = 0; nt < 2; nt++)
        bb[nt] = *(const bf16x8*)&Bt[(wn + nt * 16 + m16) * 72 + k];
      #pragma unroll
      for (int mt = 0; mt < 2; mt++)
        #pragma unroll
        for (int nt = 0; nt < 2; nt++)
          acc[mt][nt] = MFMA(a[mt], bb[nt], acc[mt][nt]);
    }
    __syncthreads();
  }
  // epilogue: acc + b2 -> At (reused as [64 bs][72 d] bf16), then coalesced
  #pragma unroll
  for (int nt = 0; nt < 2; nt++) {
    int dl = wn + nt * 16 + m16;
    float b2v = b2[e * DD + nt0 + dl];
    #pragma unroll
    for (int mt = 0; mt < 2; mt++)
      #pragma unroll
      for (int i = 0; i < 4; i++) {
        int bl = wm + mt * 16 + q * 4 + i;
        At[bl * 72 + dl] = f2b(acc[mt][nt][i] + b2v);
      }
  }
  __syncthreads();
  u16* dst = SO + ((size_t)e * 1024 + mt0 + row) * DD + nt0 + off;
  *(uint4*)dst = *(const uint4*)&At[row * 72 + off];
  *(uint4*)(dst + 8) = *(const uint4*)&At[row * 72 + off + 8];
}

// ------- K8: output GEMM (MFMA); combine weights precomputed by k_comb -------
__global__ __launch_bounds__(256) void k_out_mfma(
    const u16* __restrict__ slot_out, const float* __restrict__ logitsT,
    float* __restrict__ out) {
  __shared__ u16 comb[32 * 264];  // [32 tokens][256 es] K-major bf16
  __shared__ u16 sot[64 * 264];   // [64 d][256 es] K-major bf16
  int t = threadIdx.x;
  int lane = t & 63, w = t >> 6, q = lane >> 4, m16 = lane & 15;
  int id = blockIdx.x;
  int b = (id & 7) * 8 + ((id >> 3) & 7);
  int dc = id >> 6;  // 16 strips of 64 d
  // ---- stage SO^T tile once: sot[d][es] from slot_out[e][b*16+s][d] ----
  {
    int es2 = (t & 127) * 2, dh = t >> 7;
    const u16* s0 = slot_out +
        ((size_t)((es2 >> 4) * 1024 + b * 16 + (es2 & 15))) * DD +
        dc * 64 + dh * 32;
    const u16* s1 = s0 + DD;  // es2+1: same e, s+1 (es2 even)
    #pragma unroll
    for (int k2 = 0; k2 < 8; k2++) {
      ushort4 r0 = *(const ushort4*)(s0 + k2 * 4);
      ushort4 r1 = *(const ushort4*)(s1 + k2 * 4);
      int dl = dh * 32 + k2 * 4;
      *(u32*)&sot[(dl + 0) * 264 + es2] = (u32)r0.x | ((u32)r1.x << 16);
      *(u32*)&sot[(dl + 1) * 264 + es2] = (u32)r0.y | ((u32)r1.y << 16);
      *(u32*)&sot[(dl + 2) * 264 + es2] = (u32)r0.z | ((u32)r1.z << 16);
      *(u32*)&sot[(dl + 3) * 264 + es2] = (u32)r0.w | ((u32)r1.w << 16);
    }
  }
  for (int nch = 0; nch < 8; nch++) {
    int n0 = nch * 32;
    __syncthreads();  // sot staged (iter 0) / prev GEMM done with comb (iter>0)
    // ---- load precomputed combine weights (fp32, L2-hot) -> bf16 LDS ----
    {
      int j = t & 31, ch = t >> 5;
      const float* base = logitsT + (size_t)(ch * 32) * BN + b * 256 + n0 + j;
      float lv[32];
      #pragma unroll
      for (int i = 0; i < 32; i++) lv[i] = base[(size_t)i * BN];
      #pragma unroll
      for (int i2 = 0; i2 < 8; i2++) {
        uint2 pk;
        pk.x = (u32)f2b(lv[i2 * 4]) | ((u32)f2b(lv[i2 * 4 + 1]) << 16);
        pk.y = (u32)f2b(lv[i2 * 4 + 2]) | ((u32)f2b(lv[i2 * 4 + 3]) << 16);
        *(uint2*)&comb[j * 264 + ch * 32 + i2 * 4] = pk;
      }
    }
    __syncthreads();
    // ---- GEMM: out[32 n][64 d] = comb @ sot^T over K=256 es ----
    f32x4 aA = {0.f, 0.f, 0.f, 0.f}, aB = {0.f, 0.f, 0.f, 0.f};
    #pragma unroll
    for (int ks = 0; ks < 8; ks++) {
      bf16x8 bb = *(const bf16x8*)&sot[(w * 16 + m16) * 264 + ks * 32 + q * 8];
      bf16x8 a0 = *(const bf16x8*)&comb[m16 * 264 + ks * 32 + q * 8];
      bf16x8 a1 = *(const bf16x8*)&comb[(16 + m16) * 264 + ks * 32 + q * 8];
      aA = MFMA(a0, bb, aA);
      aB = MFMA(a1, bb, aB);
    }
    int d = dc * 64 + w * 16 + m16;
    #pragma unroll
    for (int i = 0; i < 4; i++) {
      out[((size_t)b * NN + n0 + q * 4 + i) * DD + d] = aA[i];
      out[((size_t)b * NN + n0 + 16 + q * 4 + i) * DD + d] = aB[i];
    }
  }
}

extern "C" void kernel_launch(void* const* d_in, const int* in_sizes, int n_in,
                              void* d_out, int out_size, void* d_ws, size_t ws_size,
                              hipStream_t stream) {
  const float* x     = (const float*)d_in[0];
  const float* gamma = (const float*)d_in[1];
  const float* beta  = (const float*)d_in[2];
  const float* mu    = (const float*)d_in[3];
  const float* scale = (const float*)d_in[4];
  const float* w1    = (const float*)d_in[5];
  const float* b1    = (const float*)d_in[6];
  const float* w2    = (const float*)d_in[7];
  const float* b2    = (const float*)d_in[8];
  float* out = (float*)d_out;

  // ws: SI/SO bf16 [16e][1024 bs][1024 d] @0 (33,554,432; SI then SO overwrite)
  //     logitsT fp32 [256 es][16384 bn] @33,554,432 (16,777,216)
  //     mean @50,331,648 | rstd @50,397,184 | fct @50,462,720 (64 KB each)
  //     rmun @50,528,256 | c3 @50,529,280 | c4 @50,530,304 (1 KB each)
  const size_t WS_NEED = 50531328;
  if (ws_size < WS_NEED) return;
  char* ws = (char*)d_ws;
  u16*   sislot  = (u16*)(ws);          // SI, later SO
  float* logitsT = (float*)(ws + 33554432);
  float* mean_   = (float*)(ws + 50331648);
  float* rstd_   = (float*)(ws + 50397184);
  float* fct_    = (float*)(ws + 50462720);
  float* rmun    = (float*)(ws + 50528256);
  float* c3      = (float*)(ws + 50529280);
  float* c4      = (float*)(ws + 50530304);

  // d_out as scratch until k_out_mfma overwrites with final fp32 out:
  //   xT bf16 [1024][16384] @0 (33,554,432)
  //   w1T @33,554,432 (8,388,608) | w2T @41,943,040 (8,388,608)
  //   dispW bf16 [64b][256es][256n] @50,331,648 (8,388,608)
  //   H region @58,720,256 (8,388,608): holds muT (@58,720,256, 524,288) and
  //   c1g (@59,244,544, 65,536) until k_slotin done; then k_mlp1 writes H here.
  char* sc = (char*)d_out;
  u16* xT    = (u16*)(sc);
  u16* w1T   = (u16*)(sc + 33554432);
  u16* w2T   = (u16*)(sc + 41943040);
  u16* dispW = (u16*)(sc + 50331648);
  u16* muT   = (u16*)(sc + 58720256);
  float* c1g = (float*)(sc + 59244544);
  u16* Hbuf  = (u16*)(sc + 58720256);

  k_stats<<<BN, 256, 0, stream>>>(x, gamma, beta, scale, mean_, rstd_, fct_);
  k_rmun<<<ES, 256, 0, stream>>>(mu, gamma, beta, rmun, c3, c4);
  k_mut<<<16, 256, 0, stream>>>(mu, gamma, rmun, muT);
  k_xt<<<BN / 64, 256, 0, stream>>>(x, xT);
  k_tr<<<dim3(64, EE), 256, 0, stream>>>(w1, w1T, DD, HH);  // w1T[e][h][d]
  k_tr<<<dim3(64, EE), 256, 0, stream>>>(w2, w2T, HH, DD);  // w2T[e][d][h]
  k_logits_mfma<<<BN / 16, 256, 0, stream>>>(x, muT, mean_, rstd_, fct_,
                                             c3, c4, logitsT);
  k_disp<<<dim3(EE, BB), 256, 0, stream>>>(logitsT, mean_, rstd_, dispW, c1g);
  k_comb<<<dim3(4, BB), 256, 0, stream>>>(logitsT);
  k_slotin<<<dim3(8, BB), 256, 0, stream>>>(xT, dispW, c1g, gamma, beta, sislot);
  k_mlp1<<<dim3(4, 16, EE), 256, 0, stream>>>(sislot, w1T, b1, Hbuf);
  k_mlp2<<<dim3(16, 16, EE), 256, 0, stream>>>(Hbuf, w2T, b2, sislot);
  k_out_mfma<<<dim3(1024), 256, 0, stream>>>(sislot, logitsT, out);
}

// Round 11
// 358.137 us; speedup vs baseline: 1.1008x; 1.1008x over previous
//
#include <hip/hip_runtime.h>

#define DD 1024
#define NN 256
#define BB 64
#define EE 16
#define SS 16
#define HH 256
#define ES 256
#define BN 16384

typedef unsigned short u16;
typedef unsigned int u32;
typedef __attribute__((ext_vector_type(8))) short bf16x8;
typedef __attribute__((ext_vector_type(4))) float f32x4;

#define MFMA(a, b, c) __builtin_amdgcn_mfma_f32_16x16x32_bf16(a, b, c, 0, 0, 0)

__device__ __forceinline__ u16 f2b(float f) {
  union { float f; u32 i; } c; c.f = f;
  u32 i = c.i;
  u32 r = (i + 0x7FFFu + ((i >> 16) & 1u)) >> 16;
  return (u16)r;
}

// block = 256 threads (4 waves). Sums v across the block, result broadcast.
__device__ __forceinline__ float bredsum(float v, float* red) {
  #pragma unroll
  for (int o = 32; o > 0; o >>= 1) v += __shfl_down(v, o, 64);
  __syncthreads();
  if ((threadIdx.x & 63) == 0) red[threadIdx.x >> 6] = v;
  __syncthreads();
  return red[0] + red[1] + red[2] + red[3];
}

// ---------------- K1: per-token LN stats + l2 factor ----------------
__global__ __launch_bounds__(256) void k_stats(
    const float* __restrict__ x, const float* __restrict__ gamma,
    const float* __restrict__ beta, const float* __restrict__ scale,
    float* __restrict__ mean_, float* __restrict__ rstd_,
    float* __restrict__ fct_) {
  __shared__ float red[4];
  int bn = blockIdx.x, t = threadIdx.x;
  float4 u = ((const float4*)(x + (size_t)bn * DD))[t];
  float s = u.x + u.y + u.z + u.w;
  float ss = u.x * u.x + u.y * u.y + u.z * u.z + u.w * u.w;
  s = bredsum(s, red);
  ss = bredsum(ss, red);
  float mean = s * (1.0f / DD);
  float var = ss * (1.0f / DD) - mean * mean;
  float rstd = rsqrtf(var + 1e-5f);
  float4 g = ((const float4*)gamma)[t];
  float4 be = ((const float4*)beta)[t];
  float x0 = (u.x - mean) * rstd * g.x + be.x;
  float x1 = (u.y - mean) * rstd * g.y + be.y;
  float x2 = (u.z - mean) * rstd * g.z + be.z;
  float x3 = (u.w - mean) * rstd * g.w + be.w;
  float s2 = x0 * x0 + x1 * x1 + x2 * x2 + x3 * x3;
  s2 = bredsum(s2, red);
  float f = scale[0] / fmaxf(sqrtf(s2), 1e-12f);
  if (t == 0) { mean_[bn] = mean; rstd_[bn] = rstd; fct_[bn] = f; }
}

// ------- K2: rmun[es] = 1/max(||mu[:,es]||,eps); c3 = rmun*sum(g*mu); c4 = rmun*sum(be*mu)
__global__ __launch_bounds__(256) void k_rmun(
    const float* __restrict__ mu, const float* __restrict__ gamma,
    const float* __restrict__ beta, float* __restrict__ rmun,
    float* __restrict__ c3, float* __restrict__ c4) {
  __shared__ float red[4];
  int es = blockIdx.x, t = threadIdx.x;
  float ss = 0.f, s3 = 0.f, s4 = 0.f;
  #pragma unroll
  for (int j = 0; j < 4; j++) {
    int d = t + j * 256;
    float v = mu[(size_t)d * ES + es];
    ss += v * v;
    s3 += gamma[d] * v;
    s4 += beta[d] * v;
  }
  ss = bredsum(ss, red);
  s3 = bredsum(s3, red);
  s4 = bredsum(s4, red);
  if (t == 0) {
    float r = 1.0f / fmaxf(sqrtf(ss), 1e-12f);
    rmun[es] = r;
    c3[es] = s3 * r;
    c4[es] = s4 * r;
  }
}

// ------- K3: muT[es][d] = mu[d][es]*rmun[es]*gamma[d] (bf16, K-major) -------
__global__ __launch_bounds__(256) void k_mut(
    const float* __restrict__ mu, const float* __restrict__ gamma,
    const float* __restrict__ rmun, u16* __restrict__ muT) {
  __shared__ u16 L[256 * 70];
  int t = threadIdx.x;
  int d0 = blockIdx.x * 64;
  float rm = rmun[t];
  for (int i = 0; i < 64; i++) {
    int d = d0 + i;
    float gv = gamma[d];
    L[t * 70 + i] = f2b(mu[(size_t)d * ES + t] * rm * gv);
  }
  __syncthreads();
  u32 buf[32];
  #pragma unroll
  for (int k2 = 0; k2 < 32; k2++)
    buf[k2] = *(const u32*)&L[t * 70 + k2 * 2];
  u16* dst = muT + (size_t)t * DD + d0;
  #pragma unroll
  for (int k4 = 0; k4 < 8; k4++) {
    uint4 o;
    o.x = buf[k4 * 4]; o.y = buf[k4 * 4 + 1];
    o.z = buf[k4 * 4 + 2]; o.w = buf[k4 * 4 + 3];
    *(uint4*)(dst + k4 * 8) = o;
  }
}

// ------- K4: xT[d][bn] = bf16(x[bn][d]) — raw-x transpose -------
__global__ __launch_bounds__(256) void k_xt(
    const float* __restrict__ x, u16* __restrict__ xT) {
  __shared__ u16 L[256 * 70];
  int t = threadIdx.x;
  int bn0 = blockIdx.x * 64;
  for (int cch = 0; cch < 4; cch++) {
    __syncthreads();
    for (int r = 0; r < 64; r++)
      L[t * 70 + r] = f2b(x[(size_t)(bn0 + r) * DD + cch * 256 + t]);
    __syncthreads();
    u32 buf[32];
    #pragma unroll
    for (int k2 = 0; k2 < 32; k2++)
      buf[k2] = *(const u32*)&L[t * 70 + k2 * 2];
    u16* dst = xT + (size_t)(cch * 256 + t) * BN + bn0;
    #pragma unroll
    for (int k4 = 0; k4 < 8; k4++) {
      uint4 o;
      o.x = buf[k4 * 4]; o.y = buf[k4 * 4 + 1];
      o.z = buf[k4 * 4 + 2]; o.w = buf[k4 * 4 + 3];
      *(uint4*)(dst + k4 * 8) = o;
    }
  }
}

// ------- K5: generic per-expert transpose: src[e][R][C] fp32 -> dst[e][C][R] bf16
__global__ __launch_bounds__(256) void k_tr(
    const float* __restrict__ src, u16* __restrict__ dst, int R, int C) {
  __shared__ u16 T[64 * 70];
  int t = threadIdx.x;
  int e = blockIdx.y;
  int tR = R >> 6;
  int r0 = (blockIdx.x % tR) * 64;
  int c0 = (blockIdx.x / tR) * 64;
  #pragma unroll
  for (int i = 0; i < 16; i++) {
    int r = r0 + i * 4 + (t >> 6);
    int c = t & 63;
    T[c * 70 + i * 4 + (t >> 6)] = f2b(src[((size_t)e * R + r) * C + c0 + c]);
  }
  __syncthreads();
  int cl = t >> 2, rsg = (t & 3) * 16;
  u32 buf[8];
  #pragma unroll
  for (int k2 = 0; k2 < 8; k2++)
    buf[k2] = *(const u32*)&T[cl * 70 + rsg + k2 * 2];
  u16* dp = dst + ((size_t)e * C + c0 + cl) * R + r0 + rsg;
  uint4 o0, o1;
  o0.x = buf[0]; o0.y = buf[1]; o0.z = buf[2]; o0.w = buf[3];
  o1.x = buf[4]; o1.y = buf[5]; o1.z = buf[6]; o1.w = buf[7];
  *(uint4*)dp = o0;
  *(uint4*)(dp + 8) = o1;
}

// ------- K6: logitsT[es][bn] via MFMA: fct*(rs*(X.MU') - rs*mn*c3 + c4) -------
// 64-token strip x 64-es chunk (blockIdx.y): grid (256,4)=1024 blocks (4/CU,
// 16 waves/CU). Wave owns 16 es -> 1 muT a-load reused over 4 bb MFMAs (1:4
// amortization — round-10's 16-token variant broke this to 1:1 and regressed).
__global__ __launch_bounds__(256) void k_logits_mfma(
    const float* __restrict__ x, const u16* __restrict__ muT,
    const float* __restrict__ mean_, const float* __restrict__ rstd_,
    const float* __restrict__ fct_, const float* __restrict__ c3,
    const float* __restrict__ c4, float* __restrict__ logitsT) {
  __shared__ u16 xb[64 * 136];  // [64 bn][128 k] bf16, K-major, pad 8
  int t = threadIdx.x;
  int lane = t & 63, w = t >> 6, q = lane >> 4, m16 = lane & 15;
  int bn0 = blockIdx.x * 64;
  int es0 = blockIdx.y * 64 + w * 16;
  f32x4 z = {0.f, 0.f, 0.f, 0.f};
  f32x4 acc[4];
  #pragma unroll
  for (int nt = 0; nt < 4; nt++) acc[nt] = z;
  int sr = t >> 5, cc = (t & 31) * 4;
  float4 pf[8];
  #pragma unroll
  for (int it = 0; it < 8; it++)
    pf[it] = *(const float4*)(x + (size_t)(bn0 + sr + it * 8) * DD + cc);
  for (int kb = 0; kb < 8; kb++) {
    __syncthreads();
    #pragma unroll
    for (int it = 0; it < 8; it++) {
      int row = sr + it * 8;
      uint2 pk;
      pk.x = (u32)f2b(pf[it].x) | ((u32)f2b(pf[it].y) << 16);
      pk.y = (u32)f2b(pf[it].z) | ((u32)f2b(pf[it].w) << 16);
      *(uint2*)&xb[row * 136 + cc] = pk;
    }
    __syncthreads();
    if (kb < 7) {
      #pragma unroll
      for (int it = 0; it < 8; it++)
        pf[it] = *(const float4*)(x + (size_t)(bn0 + sr + it * 8) * DD +
                                  (kb + 1) * 128 + cc);
    }
    #pragma unroll
    for (int ks = 0; ks < 4; ks++) {
      int k = ks * 32 + q * 8;
      bf16x8 a = *(const bf16x8*)(muT + (size_t)(es0 + m16) * DD +
                                  kb * 128 + k);
      #pragma unroll
      for (int nt = 0; nt < 4; nt++) {
        bf16x8 bb = *(const bf16x8*)&xb[(nt * 16 + m16) * 136 + k];
        acc[nt] = MFMA(a, bb, acc[nt]);
      }
    }
  }
  #pragma unroll
  for (int nt = 0; nt < 4; nt++) {
    int bn = bn0 + nt * 16 + m16;
    float fv = fct_[bn], rv = rstd_[bn], mv = mean_[bn];
    #pragma unroll
    for (int i = 0; i < 4; i++) {
      int es = es0 + q * 4 + i;
      float val = fv * (rv * acc[nt][i] - rv * mv * c3[es] + c4[es]);
      logitsT[(size_t)es * BN + bn] = val;
    }
  }
}

// ------- K6b: dispatch softmax -> dispW[b][es][n] bf16 (K-major n) + c1g[b][es]
__global__ __launch_bounds__(256) void k_disp(
    const float* __restrict__ logitsT, const float* __restrict__ mean_,
    const float* __restrict__ rstd_, u16* __restrict__ dispW,
    float* __restrict__ c1g) {
  int t = threadIdx.x;
  int e = blockIdx.x, b = blockIdx.y;
  int s = t >> 4, c = t & 15;
  const float* lrow = logitsT + (size_t)(e * 16 + s) * BN + b * 256 + c * 16;
  float lv[16];
  #pragma unroll
  for (int i2 = 0; i2 < 4; i2++) {
    float4 f = *(const float4*)(lrow + i2 * 4);
    lv[i2 * 4 + 0] = f.x; lv[i2 * 4 + 1] = f.y;
    lv[i2 * 4 + 2] = f.z; lv[i2 * 4 + 3] = f.w;
  }
  float mx = -1e30f;
  #pragma unroll
  for (int i = 0; i < 16; i++) mx = fmaxf(mx, lv[i]);
  #pragma unroll
  for (int o = 1; o < 16; o <<= 1) mx = fmaxf(mx, __shfl_xor(mx, o, 64));
  float sum = 0.f;
  #pragma unroll
  for (int i = 0; i < 16; i++) { lv[i] = __expf(lv[i] - mx); sum += lv[i]; }
  #pragma unroll
  for (int o = 1; o < 16; o <<= 1) sum += __shfl_xor(sum, o, 64);
  float inv = 1.0f / sum;
  float c1p = 0.f;
  u16 wp[16];
  #pragma unroll
  for (int i = 0; i < 16; i++) {
    int n = c * 16 + i;
    float wv = lv[i] * inv * rstd_[b * 256 + n];
    c1p += wv * mean_[b * 256 + n];
    wp[i] = f2b(wv);
  }
  #pragma unroll
  for (int o = 1; o < 16; o <<= 1) c1p += __shfl_xor(c1p, o, 64);
  if (c == 0) c1g[(b << 8) + e * 16 + s] = c1p;
  u16* drow = dispW + ((size_t)(b * 256 + e * 16 + s)) * 256 + c * 16;
  #pragma unroll
  for (int i2 = 0; i2 < 4; i2++) {
    uint2 pk;
    pk.x = (u32)wp[i2 * 4] | ((u32)wp[i2 * 4 + 1] << 16);
    pk.y = (u32)wp[i2 * 4 + 2] | ((u32)wp[i2 * 4 + 3] << 16);
    *(uint2*)(drow + i2 * 4) = pk;
  }
}

// ------- K6c: in-place combine-softmax normalization of logitsT -------
__global__ __launch_bounds__(256) void k_comb(float* __restrict__ logitsT) {
  __shared__ float red[4][64];
  int t = threadIdx.x;
  int l = t & 63, g = t >> 6;
  int bn = blockIdx.y * 256 + blockIdx.x * 64 + l;
  float* base = logitsT + (size_t)(g * 64) * BN + bn;
  float ev[64];
  float sum = 0.f;
  #pragma unroll
  for (int i = 0; i < 64; i++) {
    float e = __expf(base[(size_t)i * BN]);
    ev[i] = e;
    sum += e;
  }
  red[g][l] = sum;
  __syncthreads();
  float inv = 1.0f / (red[0][l] + red[1][l] + red[2][l] + red[3][l]);
  #pragma unroll
  for (int i = 0; i < 64; i++)
    base[(size_t)i * BN] = ev[i] * inv;
}

// ------- K7a: SI[e][b*16+s][d] = gamma*(dispW[b] @ xT - c1) + beta  (M=256) ----
__global__ __launch_bounds__(256) void k_slotin(
    const u16* __restrict__ xT, const u16* __restrict__ dispW,
    const float* __restrict__ c1g, const float* __restrict__ gamma,
    const float* __restrict__ beta, u16* __restrict__ SI) {
  __shared__ u16 xb[128 * 264];  // [128 d][256 n] pad->264 (2-way bank = free)
  int t = threadIdx.x;
  int lane = t & 63, w = t >> 6, q = lane >> 4, m16 = lane & 15;
  int d0 = blockIdx.x * 128, b = blockIdx.y;
  #pragma unroll
  for (int it = 0; it < 16; it++) {
    int c = it * 256 + t;
    int row = c >> 5, off = (c & 31) * 8;
    uint4 v = *(const uint4*)(xT + (size_t)(d0 + row) * BN + b * 256 + off);
    *(uint4*)&xb[row * 264 + off] = v;
  }
  __syncthreads();
  f32x4 z = {0.f, 0.f, 0.f, 0.f};
  f32x4 acc[4][8];
  #pragma unroll
  for (int mt = 0; mt < 4; mt++)
    #pragma unroll
    for (int nt = 0; nt < 8; nt++) acc[mt][nt] = z;
  int es0 = w * 64;
  for (int ks = 0; ks < 8; ks++) {
    int k = ks * 32 + q * 8;
    bf16x8 a[4];
    #pragma unroll
    for (int mt = 0; mt < 4; mt++)
      a[mt] = *(const bf16x8*)(dispW +
               ((size_t)(b * 256 + es0 + mt * 16 + m16)) * 256 + k);
    #pragma unroll
    for (int nt = 0; nt < 8; nt++) {
      bf16x8 bb = *(const bf16x8*)&xb[(nt * 16 + m16) * 264 + k];
      #pragma unroll
      for (int mt = 0; mt < 4; mt++) acc[mt][nt] = MFMA(a[mt], bb, acc[mt][nt]);
    }
  }
  float gv[8], bev[8];
  #pragma unroll
  for (int nt = 0; nt < 8; nt++) {
    int d = d0 + nt * 16 + m16;
    gv[nt] = gamma[d]; bev[nt] = beta[d];
  }
  #pragma unroll
  for (int mt = 0; mt < 4; mt++) {
    float c1[4];
    #pragma unroll
    for (int i = 0; i < 4; i++)
      c1[i] = c1g[(b << 8) + es0 + mt * 16 + q * 4 + i];
    #pragma unroll
    for (int nt = 0; nt < 8; nt++)
      #pragma unroll
      for (int i = 0; i < 4; i++)
        SI[((size_t)(w * 4 + mt) * 1024 + b * 16 + q * 4 + i) * DD + d0 +
           nt * 16 + m16] = f2b(gv[nt] * (acc[mt][nt][i] - c1[i]) + bev[nt]);
  }
}

// ------- K7b1: H[e][bs][h] = gelu(SI @ w1T + b1); tile 64x64, K=1024 -------
__global__ __launch_bounds__(256) void k_mlp1(
    const u16* __restrict__ SI, const u16* __restrict__ w1T,
    const float* __restrict__ b1, u16* __restrict__ H) {
  __shared__ u16 At[64 * 72];
  __shared__ u16 Bt[64 * 72];
  int t = threadIdx.x;
  int lane = t & 63, w = t >> 6, q = lane >> 4, m16 = lane & 15;
  int nt0 = blockIdx.x * 64;   // h
  int mt0 = blockIdx.y * 64;   // bs
  int e = blockIdx.z;
  int wm = (w & 1) * 32, wn = (w >> 1) * 32;
  f32x4 z = {0.f, 0.f, 0.f, 0.f};
  f32x4 acc[2][2];
  #pragma unroll
  for (int mt = 0; mt < 2; mt++)
    #pragma unroll
    for (int nt = 0; nt < 2; nt++) acc[mt][nt] = z;
  const u16* Ab = SI + ((size_t)e * 1024 + mt0) * DD;
  const u16* Bb = w1T + ((size_t)e * HH + nt0) * DD;
  int row = t >> 2, off = (t & 3) * 16;
  uint4 pa0, pa1, pb0, pb1;
  pa0 = *(const uint4*)(Ab + (size_t)row * DD + off);
  pa1 = *(const uint4*)(Ab + (size_t)row * DD + off + 8);
  pb0 = *(const uint4*)(Bb + (size_t)row * DD + off);
  pb1 = *(const uint4*)(Bb + (size_t)row * DD + off + 8);
  for (int kb = 0; kb < 16; kb++) {
    *(uint4*)&At[row * 72 + off] = pa0;
    *(uint4*)&At[row * 72 + off + 8] = pa1;
    *(uint4*)&Bt[row * 72 + off] = pb0;
    *(uint4*)&Bt[row * 72 + off + 8] = pb1;
    __syncthreads();
    if (kb < 15) {
      int k0 = (kb + 1) * 64;
      pa0 = *(const uint4*)(Ab + (size_t)row * DD + k0 + off);
      pa1 = *(const uint4*)(Ab + (size_t)row * DD + k0 + off + 8);
      pb0 = *(const uint4*)(Bb + (size_t)row * DD + k0 + off);
      pb1 = *(const uint4*)(Bb + (size_t)row * DD + k0 + off + 8);
    }
    #pragma unroll
    for (int kk = 0; kk < 2; kk++) {
      int k = kk * 32 + q * 8;
      bf16x8 a[2], bb[2];
      #pragma unroll
      for (int mt = 0; mt < 2; mt++)
        a[mt] = *(const bf16x8*)&At[(wm + mt * 16 + m16) * 72 + k];
      #pragma unroll
      for (int nt = 0; nt < 2; nt++)
        bb[nt] = *(const bf16x8*)&Bt[(wn + nt * 16 + m16) * 72 + k];
      #pragma unroll
      for (int mt = 0; mt < 2; mt++)
        #pragma unroll
        for (int nt = 0; nt < 2; nt++)
          acc[mt][nt] = MFMA(a[mt], bb[nt], acc[mt][nt]);
    }
    __syncthreads();
  }
  #pragma unroll
  for (int nt = 0; nt < 2; nt++) {
    int h = nt0 + wn + nt * 16 + m16;
    float b1v = b1[e * HH + h];
    #pragma unroll
    for (int mt = 0; mt < 2; mt++)
      #pragma unroll
      for (int i = 0; i < 4; i++) {
        float zz = acc[mt][nt][i] + b1v;
        int bs = mt0 + wm + mt * 16 + q * 4 + i;
        H[((size_t)e * 1024 + bs) * HH + h] =
            f2b(0.5f * zz * (1.0f + erff(zz * 0.70710678118654752f)));
      }
  }
}

// ------- K7b2: SO[e][bs][d] = H @ w2T + b2; tile 64x64, K=256 -------
__global__ __launch_bounds__(256) void k_mlp2(
    const u16* __restrict__ H, const u16* __restrict__ w2T,
    const float* __restrict__ b2, u16* __restrict__ SO) {
  __shared__ u16 At[64 * 72];
  __shared__ u16 Bt[64 * 72];
  int t = threadIdx.x;
  int lane = t & 63, w = t >> 6, q = lane >> 4, m16 = lane & 15;
  int nt0 = blockIdx.x * 64;   // d
  int mt0 = blockIdx.y * 64;   // bs
  int e = blockIdx.z;
  int wm = (w & 1) * 32, wn = (w >> 1) * 32;
  f32x4 z = {0.f, 0.f, 0.f, 0.f};
  f32x4 acc[2][2];
  #pragma unroll
  for (int mt = 0; mt < 2; mt++)
    #pragma unroll
    for (int nt = 0; nt < 2; nt++) acc[mt][nt] = z;
  const u16* Ab = H + ((size_t)e * 1024 + mt0) * HH;
  const u16* Bb = w2T + ((size_t)e * DD + nt0) * HH;
  int row = t >> 2, off = (t & 3) * 16;
  uint4 pa0, pa1, pb0, pb1;
  pa0 = *(const uint4*)(Ab + (size_t)row * HH + off);
  pa1 = *(const uint4*)(Ab + (size_t)row * HH + off + 8);
  pb0 = *(const uint4*)(Bb + (size_t)row * HH + off);
  pb1 = *(const uint4*)(Bb + (size_t)row * HH + off + 8);
  for (int kb = 0; kb < 4; kb++) {
    *(uint4*)&At[row * 72 + off] = pa0;
    *(uint4*)&At[row * 72 + off + 8] = pa1;
    *(uint4*)&Bt[row * 72 + off] = pb0;
    *(uint4*)&Bt[row * 72 + off + 8] = pb1;
    __syncthreads();
    if (kb < 3) {
      int k0 = (kb + 1) * 64;
      pa0 = *(const uint4*)(Ab + (size_t)row * HH + k0 + off);
      pa1 = *(const uint4*)(Ab + (size_t)row * HH + k0 + off + 8);
      pb0 = *(const uint4*)(Bb + (size_t)row * HH + k0 + off);
      pb1 = *(const uint4*)(Bb + (size_t)row * HH + k0 + off + 8);
    }
    #pragma unroll
    for (int kk = 0; kk < 2; kk++) {
      int k = kk * 32 + q * 8;
      bf16x8 a[2], bb[2];
      #pragma unroll
      for (int mt = 0; mt < 2; mt++)
        a[mt] = *(const bf16x8*)&At[(wm + mt * 16 + m16) * 72 + k];
      #pragma unroll
      for (int nt = 0; nt < 2; nt++)
        bb[nt] = *(const bf16x8*)&Bt[(wn + nt * 16 + m16) * 72 + k];
      #pragma unroll
      for (int mt = 0; mt < 2; mt++)
        #pragma unroll
        for (int nt = 0; nt < 2; nt++)
          acc[mt][nt] = MFMA(a[mt], bb[nt], acc[mt][nt]);
    }
    __syncthreads();
  }
  // epilogue: acc + b2 -> At (reused as [64 bs][72 d] bf16), then coalesced
  #pragma unroll
  for (int nt = 0; nt < 2; nt++) {
    int dl = wn + nt * 16 + m16;
    float b2v = b2[e * DD + nt0 + dl];
    #pragma unroll
    for (int mt = 0; mt < 2; mt++)
      #pragma unroll
      for (int i = 0; i < 4; i++) {
        int bl = wm + mt * 16 + q * 4 + i;
        At[bl * 72 + dl] = f2b(acc[mt][nt][i] + b2v);
      }
  }
  __syncthreads();
  u16* dst = SO + ((size_t)e * 1024 + mt0 + row) * DD + nt0 + off;
  *(uint4*)dst = *(const uint4*)&At[row * 72 + off];
  *(uint4*)(dst + 8) = *(const uint4*)&At[row * 72 + off + 8];
}

// ------- K8: output GEMM (MFMA); combine weights precomputed by k_comb -------
__global__ __launch_bounds__(256) void k_out_mfma(
    const u16* __restrict__ slot_out, const float* __restrict__ logitsT,
    float* __restrict__ out) {
  __shared__ u16 comb[32 * 264];  // [32 tokens][256 es] K-major bf16
  __shared__ u16 sot[64 * 264];   // [64 d][256 es] K-major bf16
  int t = threadIdx.x;
  int lane = t & 63, w = t >> 6, q = lane >> 4, m16 = lane & 15;
  int id = blockIdx.x;
  int b = (id & 7) * 8 + ((id >> 3) & 7);
  int dc = id >> 6;  // 16 strips of 64 d
  // ---- stage SO^T tile once: sot[d][es] from slot_out[e][b*16+s][d] ----
  {
    int es2 = (t & 127) * 2, dh = t >> 7;
    const u16* s0 = slot_out +
        ((size_t)((es2 >> 4) * 1024 + b * 16 + (es2 & 15))) * DD +
        dc * 64 + dh * 32;
    const u16* s1 = s0 + DD;  // es2+1: same e, s+1 (es2 even)
    #pragma unroll
    for (int k2 = 0; k2 < 8; k2++) {
      ushort4 r0 = *(const ushort4*)(s0 + k2 * 4);
      ushort4 r1 = *(const ushort4*)(s1 + k2 * 4);
      int dl = dh * 32 + k2 * 4;
      *(u32*)&sot[(dl + 0) * 264 + es2] = (u32)r0.x | ((u32)r1.x << 16);
      *(u32*)&sot[(dl + 1) * 264 + es2] = (u32)r0.y | ((u32)r1.y << 16);
      *(u32*)&sot[(dl + 2) * 264 + es2] = (u32)r0.z | ((u32)r1.z << 16);
      *(u32*)&sot[(dl + 3) * 264 + es2] = (u32)r0.w | ((u32)r1.w << 16);
    }
  }
  for (int nch = 0; nch < 8; nch++) {
    int n0 = nch * 32;
    __syncthreads();  // sot staged (iter 0) / prev GEMM done with comb (iter>0)
    // ---- load precomputed combine weights (fp32, L2-hot) -> bf16 LDS ----
    {
      int j = t & 31, ch = t >> 5;
      const float* base = logitsT + (size_t)(ch * 32) * BN + b * 256 + n0 + j;
      float lv[32];
      #pragma unroll
      for (int i = 0; i < 32; i++) lv[i] = base[(size_t)i * BN];
      #pragma unroll
      for (int i2 = 0; i2 < 8; i2++) {
        uint2 pk;
        pk.x = (u32)f2b(lv[i2 * 4]) | ((u32)f2b(lv[i2 * 4 + 1]) << 16);
        pk.y = (u32)f2b(lv[i2 * 4 + 2]) | ((u32)f2b(lv[i2 * 4 + 3]) << 16);
        *(uint2*)&comb[j * 264 + ch * 32 + i2 * 4] = pk;
      }
    }
    __syncthreads();
    // ---- GEMM: out[32 n][64 d] = comb @ sot^T over K=256 es ----
    f32x4 aA = {0.f, 0.f, 0.f, 0.f}, aB = {0.f, 0.f, 0.f, 0.f};
    #pragma unroll
    for (int ks = 0; ks < 8; ks++) {
      bf16x8 bb = *(const bf16x8*)&sot[(w * 16 + m16) * 264 + ks * 32 + q * 8];
      bf16x8 a0 = *(const bf16x8*)&comb[m16 * 264 + ks * 32 + q * 8];
      bf16x8 a1 = *(const bf16x8*)&comb[(16 + m16) * 264 + ks * 32 + q * 8];
      aA = MFMA(a0, bb, aA);
      aB = MFMA(a1, bb, aB);
    }
    int d = dc * 64 + w * 16 + m16;
    #pragma unroll
    for (int i = 0; i < 4; i++) {
      out[((size_t)b * NN + n0 + q * 4 + i) * DD + d] = aA[i];
      out[((size_t)b * NN + n0 + 16 + q * 4 + i) * DD + d] = aB[i];
    }
  }
}

extern "C" void kernel_launch(void* const* d_in, const int* in_sizes, int n_in,
                              void* d_out, int out_size, void* d_ws, size_t ws_size,
                              hipStream_t stream) {
  const float* x     = (const float*)d_in[0];
  const float* gamma = (const float*)d_in[1];
  const float* beta  = (const float*)d_in[2];
  const float* mu    = (const float*)d_in[3];
  const float* scale = (const float*)d_in[4];
  const float* w1    = (const float*)d_in[5];
  const float* b1    = (const float*)d_in[6];
  const float* w2    = (const float*)d_in[7];
  const float* b2    = (const float*)d_in[8];
  float* out = (float*)d_out;

  // ws: SI/SO bf16 [16e][1024 bs][1024 d] @0 (33,554,432; SI then SO overwrite)
  //     logitsT fp32 [256 es][16384 bn] @33,554,432 (16,777,216)
  //     mean @50,331,648 | rstd @50,397,184 | fct @50,462,720 (64 KB each)
  //     rmun @50,528,256 | c3 @50,529,280 | c4 @50,530,304 (1 KB each)
  const size_t WS_NEED = 50531328;
  if (ws_size < WS_NEED) return;
  char* ws = (char*)d_ws;
  u16*   sislot  = (u16*)(ws);          // SI, later SO
  float* logitsT = (float*)(ws + 33554432);
  float* mean_   = (float*)(ws + 50331648);
  float* rstd_   = (float*)(ws + 50397184);
  float* fct_    = (float*)(ws + 50462720);
  float* rmun    = (float*)(ws + 50528256);
  float* c3      = (float*)(ws + 50529280);
  float* c4      = (float*)(ws + 50530304);

  // d_out as scratch until k_out_mfma overwrites with final fp32 out:
  //   xT bf16 [1024][16384] @0 (33,554,432)
  //   w1T @33,554,432 (8,388,608) | w2T @41,943,040 (8,388,608)
  //   dispW bf16 [64b][256es][256n] @50,331,648 (8,388,608)
  //   H region @58,720,256 (8,388,608): holds muT (@58,720,256, 524,288) and
  //   c1g (@59,244,544, 65,536) until k_slotin done; then k_mlp1 writes H here.
  char* sc = (char*)d_out;
  u16* xT    = (u16*)(sc);
  u16* w1T   = (u16*)(sc + 33554432);
  u16* w2T   = (u16*)(sc + 41943040);
  u16* dispW = (u16*)(sc + 50331648);
  u16* muT   = (u16*)(sc + 58720256);
  float* c1g = (float*)(sc + 59244544);
  u16* Hbuf  = (u16*)(sc + 58720256);

  k_stats<<<BN, 256, 0, stream>>>(x, gamma, beta, scale, mean_, rstd_, fct_);
  k_rmun<<<ES, 256, 0, stream>>>(mu, gamma, beta, rmun, c3, c4);
  k_mut<<<16, 256, 0, stream>>>(mu, gamma, rmun, muT);
  k_xt<<<BN / 64, 256, 0, stream>>>(x, xT);
  k_tr<<<dim3(64, EE), 256, 0, stream>>>(w1, w1T, DD, HH);  // w1T[e][h][d]
  k_tr<<<dim3(64, EE), 256, 0, stream>>>(w2, w2T, HH, DD);  // w2T[e][d][h]
  k_logits_mfma<<<dim3(BN / 64, 4), 256, 0, stream>>>(x, muT, mean_, rstd_,
                                                      fct_, c3, c4, logitsT);
  k_disp<<<dim3(EE, BB), 256, 0, stream>>>(logitsT, mean_, rstd_, dispW, c1g);
  k_comb<<<dim3(4, BB), 256, 0, stream>>>(logitsT);
  k_slotin<<<dim3(8, BB), 256, 0, stream>>>(xT, dispW, c1g, gamma, beta, sislot);
  k_mlp1<<<dim3(4, 16, EE), 256, 0, stream>>>(sislot, w1T, b1, Hbuf);
  k_mlp2<<<dim3(16, 16, EE), 256, 0, stream>>>(Hbuf, w2T, b2, sislot);
  k_out_mfma<<<dim3(1024), 256, 0, stream>>>(sislot, logitsT, out);
}

// Round 12
// 340.223 us; speedup vs baseline: 1.1588x; 1.0527x over previous
//
#include <hip/hip_runtime.h>

#define DD 1024
#define NN 256
#define BB 64
#define EE 16
#define SS 16
#define HH 256
#define ES 256
#define BN 16384

typedef unsigned short u16;
typedef unsigned int u32;
typedef __attribute__((ext_vector_type(8))) short bf16x8;
typedef __attribute__((ext_vector_type(4))) float f32x4;

#define MFMA(a, b, c) __builtin_amdgcn_mfma_f32_16x16x32_bf16(a, b, c, 0, 0, 0)

__device__ __forceinline__ u16 f2b(float f) {
  union { float f; u32 i; } c; c.f = f;
  u32 i = c.i;
  u32 r = (i + 0x7FFFu + ((i >> 16) & 1u)) >> 16;
  return (u16)r;
}

// block = 256 threads (4 waves). Sums v across the block, result broadcast.
__device__ __forceinline__ float bredsum(float v, float* red) {
  #pragma unroll
  for (int o = 32; o > 0; o >>= 1) v += __shfl_down(v, o, 64);
  __syncthreads();
  if ((threadIdx.x & 63) == 0) red[threadIdx.x >> 6] = v;
  __syncthreads();
  return red[0] + red[1] + red[2] + red[3];
}

// ---------------- K1: per-token LN stats + l2 factor ----------------
__global__ __launch_bounds__(256) void k_stats(
    const float* __restrict__ x, const float* __restrict__ gamma,
    const float* __restrict__ beta, const float* __restrict__ scale,
    float* __restrict__ mean_, float* __restrict__ rstd_,
    float* __restrict__ fct_) {
  __shared__ float red[4];
  int bn = blockIdx.x, t = threadIdx.x;
  float4 u = ((const float4*)(x + (size_t)bn * DD))[t];
  float s = u.x + u.y + u.z + u.w;
  float ss = u.x * u.x + u.y * u.y + u.z * u.z + u.w * u.w;
  s = bredsum(s, red);
  ss = bredsum(ss, red);
  float mean = s * (1.0f / DD);
  float var = ss * (1.0f / DD) - mean * mean;
  float rstd = rsqrtf(var + 1e-5f);
  float4 g = ((const float4*)gamma)[t];
  float4 be = ((const float4*)beta)[t];
  float x0 = (u.x - mean) * rstd * g.x + be.x;
  float x1 = (u.y - mean) * rstd * g.y + be.y;
  float x2 = (u.z - mean) * rstd * g.z + be.z;
  float x3 = (u.w - mean) * rstd * g.w + be.w;
  float s2 = x0 * x0 + x1 * x1 + x2 * x2 + x3 * x3;
  s2 = bredsum(s2, red);
  float f = scale[0] / fmaxf(sqrtf(s2), 1e-12f);
  if (t == 0) { mean_[bn] = mean; rstd_[bn] = rstd; fct_[bn] = f; }
}

// ------- K2: rmun[es] = 1/max(||mu[:,es]||,eps); c3 = rmun*sum(g*mu); c4 = rmun*sum(be*mu)
__global__ __launch_bounds__(256) void k_rmun(
    const float* __restrict__ mu, const float* __restrict__ gamma,
    const float* __restrict__ beta, float* __restrict__ rmun,
    float* __restrict__ c3, float* __restrict__ c4) {
  __shared__ float red[4];
  int es = blockIdx.x, t = threadIdx.x;
  float ss = 0.f, s3 = 0.f, s4 = 0.f;
  #pragma unroll
  for (int j = 0; j < 4; j++) {
    int d = t + j * 256;
    float v = mu[(size_t)d * ES + es];
    ss += v * v;
    s3 += gamma[d] * v;
    s4 += beta[d] * v;
  }
  ss = bredsum(ss, red);
  s3 = bredsum(s3, red);
  s4 = bredsum(s4, red);
  if (t == 0) {
    float r = 1.0f / fmaxf(sqrtf(ss), 1e-12f);
    rmun[es] = r;
    c3[es] = s3 * r;
    c4[es] = s4 * r;
  }
}

// ------- K3: muT[es][d] = mu[d][es]*rmun[es]*gamma[d] (bf16, K-major) -------
__global__ __launch_bounds__(256) void k_mut(
    const float* __restrict__ mu, const float* __restrict__ gamma,
    const float* __restrict__ rmun, u16* __restrict__ muT) {
  __shared__ u16 L[256 * 70];
  int t = threadIdx.x;
  int d0 = blockIdx.x * 64;
  float rm = rmun[t];
  for (int i = 0; i < 64; i++) {
    int d = d0 + i;
    float gv = gamma[d];
    L[t * 70 + i] = f2b(mu[(size_t)d * ES + t] * rm * gv);
  }
  __syncthreads();
  u32 buf[32];
  #pragma unroll
  for (int k2 = 0; k2 < 32; k2++)
    buf[k2] = *(const u32*)&L[t * 70 + k2 * 2];
  u16* dst = muT + (size_t)t * DD + d0;
  #pragma unroll
  for (int k4 = 0; k4 < 8; k4++) {
    uint4 o;
    o.x = buf[k4 * 4]; o.y = buf[k4 * 4 + 1];
    o.z = buf[k4 * 4 + 2]; o.w = buf[k4 * 4 + 3];
    *(uint4*)(dst + k4 * 8) = o;
  }
}

// ------- K4: xT[d][bn] = bf16(x[bn][d]) — raw-x transpose -------
// cch split across blockIdx.y: grid (256,4)=1024 blocks (4/CU, 16 waves/CU)
// — was 256 blocks (1/CU, 9.4% occupancy, latency-bound at 42.5us vs ~10us
// BW floor). Straight-line body, one barrier (was 4-iter loop, 8 barriers).
__global__ __launch_bounds__(256) void k_xt(
    const float* __restrict__ x, u16* __restrict__ xT) {
  __shared__ u16 L[256 * 70];
  int t = threadIdx.x;
  int bn0 = blockIdx.x * 64;
  int cch = blockIdx.y;
  for (int r = 0; r < 64; r++)
    L[t * 70 + r] = f2b(x[(size_t)(bn0 + r) * DD + cch * 256 + t]);
  __syncthreads();
  u32 buf[32];
  #pragma unroll
  for (int k2 = 0; k2 < 32; k2++)
    buf[k2] = *(const u32*)&L[t * 70 + k2 * 2];
  u16* dst = xT + (size_t)(cch * 256 + t) * BN + bn0;
  #pragma unroll
  for (int k4 = 0; k4 < 8; k4++) {
    uint4 o;
    o.x = buf[k4 * 4]; o.y = buf[k4 * 4 + 1];
    o.z = buf[k4 * 4 + 2]; o.w = buf[k4 * 4 + 3];
    *(uint4*)(dst + k4 * 8) = o;
  }
}

// ------- K5: generic per-expert transpose: src[e][R][C] fp32 -> dst[e][C][R] bf16
__global__ __launch_bounds__(256) void k_tr(
    const float* __restrict__ src, u16* __restrict__ dst, int R, int C) {
  __shared__ u16 T[64 * 70];
  int t = threadIdx.x;
  int e = blockIdx.y;
  int tR = R >> 6;
  int r0 = (blockIdx.x % tR) * 64;
  int c0 = (blockIdx.x / tR) * 64;
  #pragma unroll
  for (int i = 0; i < 16; i++) {
    int r = r0 + i * 4 + (t >> 6);
    int c = t & 63;
    T[c * 70 + i * 4 + (t >> 6)] = f2b(src[((size_t)e * R + r) * C + c0 + c]);
  }
  __syncthreads();
  int cl = t >> 2, rsg = (t & 3) * 16;
  u32 buf[8];
  #pragma unroll
  for (int k2 = 0; k2 < 8; k2++)
    buf[k2] = *(const u32*)&T[cl * 70 + rsg + k2 * 2];
  u16* dp = dst + ((size_t)e * C + c0 + cl) * R + r0 + rsg;
  uint4 o0, o1;
  o0.x = buf[0]; o0.y = buf[1]; o0.z = buf[2]; o0.w = buf[3];
  o1.x = buf[4]; o1.y = buf[5]; o1.z = buf[6]; o1.w = buf[7];
  *(uint4*)dp = o0;
  *(uint4*)(dp + 8) = o1;
}

// ------- K6: logitsT[es][bn] via MFMA: fct*(rs*(X.MU') - rs*mn*c3 + c4) -------
// 64-token strip x 64-es chunk (blockIdx.y): grid (256,4)=1024 blocks (4/CU,
// 16 waves/CU). Wave owns 16 es -> 1 muT a-load reused over 4 bb MFMAs (1:4
// amortization — round-10's 16-token variant broke this to 1:1 and regressed).
__global__ __launch_bounds__(256) void k_logits_mfma(
    const float* __restrict__ x, const u16* __restrict__ muT,
    const float* __restrict__ mean_, const float* __restrict__ rstd_,
    const float* __restrict__ fct_, const float* __restrict__ c3,
    const float* __restrict__ c4, float* __restrict__ logitsT) {
  __shared__ u16 xb[64 * 136];  // [64 bn][128 k] bf16, K-major, pad 8
  int t = threadIdx.x;
  int lane = t & 63, w = t >> 6, q = lane >> 4, m16 = lane & 15;
  int bn0 = blockIdx.x * 64;
  int es0 = blockIdx.y * 64 + w * 16;
  f32x4 z = {0.f, 0.f, 0.f, 0.f};
  f32x4 acc[4];
  #pragma unroll
  for (int nt = 0; nt < 4; nt++) acc[nt] = z;
  int sr = t >> 5, cc = (t & 31) * 4;
  float4 pf[8];
  #pragma unroll
  for (int it = 0; it < 8; it++)
    pf[it] = *(const float4*)(x + (size_t)(bn0 + sr + it * 8) * DD + cc);
  for (int kb = 0; kb < 8; kb++) {
    __syncthreads();
    #pragma unroll
    for (int it = 0; it < 8; it++) {
      int row = sr + it * 8;
      uint2 pk;
      pk.x = (u32)f2b(pf[it].x) | ((u32)f2b(pf[it].y) << 16);
      pk.y = (u32)f2b(pf[it].z) | ((u32)f2b(pf[it].w) << 16);
      *(uint2*)&xb[row * 136 + cc] = pk;
    }
    __syncthreads();
    if (kb < 7) {
      #pragma unroll
      for (int it = 0; it < 8; it++)
        pf[it] = *(const float4*)(x + (size_t)(bn0 + sr + it * 8) * DD +
                                  (kb + 1) * 128 + cc);
    }
    #pragma unroll
    for (int ks = 0; ks < 4; ks++) {
      int k = ks * 32 + q * 8;
      bf16x8 a = *(const bf16x8*)(muT + (size_t)(es0 + m16) * DD +
                                  kb * 128 + k);
      #pragma unroll
      for (int nt = 0; nt < 4; nt++) {
        bf16x8 bb = *(const bf16x8*)&xb[(nt * 16 + m16) * 136 + k];
        acc[nt] = MFMA(a, bb, acc[nt]);
      }
    }
  }
  #pragma unroll
  for (int nt = 0; nt < 4; nt++) {
    int bn = bn0 + nt * 16 + m16;
    float fv = fct_[bn], rv = rstd_[bn], mv = mean_[bn];
    #pragma unroll
    for (int i = 0; i < 4; i++) {
      int es = es0 + q * 4 + i;
      float val = fv * (rv * acc[nt][i] - rv * mv * c3[es] + c4[es]);
      logitsT[(size_t)es * BN + bn] = val;
    }
  }
}

// ------- K6b: dispatch softmax -> dispW[b][es][n] bf16 (K-major n) + c1g[b][es]
__global__ __launch_bounds__(256) void k_disp(
    const float* __restrict__ logitsT, const float* __restrict__ mean_,
    const float* __restrict__ rstd_, u16* __restrict__ dispW,
    float* __restrict__ c1g) {
  int t = threadIdx.x;
  int e = blockIdx.x, b = blockIdx.y;
  int s = t >> 4, c = t & 15;
  const float* lrow = logitsT + (size_t)(e * 16 + s) * BN + b * 256 + c * 16;
  float lv[16];
  #pragma unroll
  for (int i2 = 0; i2 < 4; i2++) {
    float4 f = *(const float4*)(lrow + i2 * 4);
    lv[i2 * 4 + 0] = f.x; lv[i2 * 4 + 1] = f.y;
    lv[i2 * 4 + 2] = f.z; lv[i2 * 4 + 3] = f.w;
  }
  float mx = -1e30f;
  #pragma unroll
  for (int i = 0; i < 16; i++) mx = fmaxf(mx, lv[i]);
  #pragma unroll
  for (int o = 1; o < 16; o <<= 1) mx = fmaxf(mx, __shfl_xor(mx, o, 64));
  float sum = 0.f;
  #pragma unroll
  for (int i = 0; i < 16; i++) { lv[i] = __expf(lv[i] - mx); sum += lv[i]; }
  #pragma unroll
  for (int o = 1; o < 16; o <<= 1) sum += __shfl_xor(sum, o, 64);
  float inv = 1.0f / sum;
  float c1p = 0.f;
  u16 wp[16];
  #pragma unroll
  for (int i = 0; i < 16; i++) {
    int n = c * 16 + i;
    float wv = lv[i] * inv * rstd_[b * 256 + n];
    c1p += wv * mean_[b * 256 + n];
    wp[i] = f2b(wv);
  }
  #pragma unroll
  for (int o = 1; o < 16; o <<= 1) c1p += __shfl_xor(c1p, o, 64);
  if (c == 0) c1g[(b << 8) + e * 16 + s] = c1p;
  u16* drow = dispW + ((size_t)(b * 256 + e * 16 + s)) * 256 + c * 16;
  #pragma unroll
  for (int i2 = 0; i2 < 4; i2++) {
    uint2 pk;
    pk.x = (u32)wp[i2 * 4] | ((u32)wp[i2 * 4 + 1] << 16);
    pk.y = (u32)wp[i2 * 4 + 2] | ((u32)wp[i2 * 4 + 3] << 16);
    *(uint2*)(drow + i2 * 4) = pk;
  }
}

// ------- K6c: in-place combine-softmax normalization of logitsT -------
__global__ __launch_bounds__(256) void k_comb(float* __restrict__ logitsT) {
  __shared__ float red[4][64];
  int t = threadIdx.x;
  int l = t & 63, g = t >> 6;
  int bn = blockIdx.y * 256 + blockIdx.x * 64 + l;
  float* base = logitsT + (size_t)(g * 64) * BN + bn;
  float ev[64];
  float sum = 0.f;
  #pragma unroll
  for (int i = 0; i < 64; i++) {
    float e = __expf(base[(size_t)i * BN]);
    ev[i] = e;
    sum += e;
  }
  red[g][l] = sum;
  __syncthreads();
  float inv = 1.0f / (red[0][l] + red[1][l] + red[2][l] + red[3][l]);
  #pragma unroll
  for (int i = 0; i < 64; i++)
    base[(size_t)i * BN] = ev[i] * inv;
}

// ------- K7a: SI[e][b*16+s][d] = gamma*(dispW[b] @ xT - c1) + beta  (M=256) ----
__global__ __launch_bounds__(256) void k_slotin(
    const u16* __restrict__ xT, const u16* __restrict__ dispW,
    const float* __restrict__ c1g, const float* __restrict__ gamma,
    const float* __restrict__ beta, u16* __restrict__ SI) {
  __shared__ u16 xb[128 * 264];  // [128 d][256 n] pad->264 (2-way bank = free)
  int t = threadIdx.x;
  int lane = t & 63, w = t >> 6, q = lane >> 4, m16 = lane & 15;
  int d0 = blockIdx.x * 128, b = blockIdx.y;
  #pragma unroll
  for (int it = 0; it < 16; it++) {
    int c = it * 256 + t;
    int row = c >> 5, off = (c & 31) * 8;
    uint4 v = *(const uint4*)(xT + (size_t)(d0 + row) * BN + b * 256 + off);
    *(uint4*)&xb[row * 264 + off] = v;
  }
  __syncthreads();
  f32x4 z = {0.f, 0.f, 0.f, 0.f};
  f32x4 acc[4][8];
  #pragma unroll
  for (int mt = 0; mt < 4; mt++)
    #pragma unroll
    for (int nt = 0; nt < 8; nt++) acc[mt][nt] = z;
  int es0 = w * 64;
  for (int ks = 0; ks < 8; ks++) {
    int k = ks * 32 + q * 8;
    bf16x8 a[4];
    #pragma unroll
    for (int mt = 0; mt < 4; mt++)
      a[mt] = *(const bf16x8*)(dispW +
               ((size_t)(b * 256 + es0 + mt * 16 + m16)) * 256 + k);
    #pragma unroll
    for (int nt = 0; nt < 8; nt++) {
      bf16x8 bb = *(const bf16x8*)&xb[(nt * 16 + m16) * 264 + k];
      #pragma unroll
      for (int mt = 0; mt < 4; mt++) acc[mt][nt] = MFMA(a[mt], bb, acc[mt][nt]);
    }
  }
  float gv[8], bev[8];
  #pragma unroll
  for (int nt = 0; nt < 8; nt++) {
    int d = d0 + nt * 16 + m16;
    gv[nt] = gamma[d]; bev[nt] = beta[d];
  }
  #pragma unroll
  for (int mt = 0; mt < 4; mt++) {
    float c1[4];
    #pragma unroll
    for (int i = 0; i < 4; i++)
      c1[i] = c1g[(b << 8) + es0 + mt * 16 + q * 4 + i];
    #pragma unroll
    for (int nt = 0; nt < 8; nt++)
      #pragma unroll
      for (int i = 0; i < 4; i++)
        SI[((size_t)(w * 4 + mt) * 1024 + b * 16 + q * 4 + i) * DD + d0 +
           nt * 16 + m16] = f2b(gv[nt] * (acc[mt][nt][i] - c1[i]) + bev[nt]);
  }
}

// ------- K7b1: H[e][bs][h] = gelu(SI @ w1T + b1); tile 64x64, K=1024 -------
__global__ __launch_bounds__(256) void k_mlp1(
    const u16* __restrict__ SI, const u16* __restrict__ w1T,
    const float* __restrict__ b1, u16* __restrict__ H) {
  __shared__ u16 At[64 * 72];
  __shared__ u16 Bt[64 * 72];
  int t = threadIdx.x;
  int lane = t & 63, w = t >> 6, q = lane >> 4, m16 = lane & 15;
  int nt0 = blockIdx.x * 64;   // h
  int mt0 = blockIdx.y * 64;   // bs
  int e = blockIdx.z;
  int wm = (w & 1) * 32, wn = (w >> 1) * 32;
  f32x4 z = {0.f, 0.f, 0.f, 0.f};
  f32x4 acc[2][2];
  #pragma unroll
  for (int mt = 0; mt < 2; mt++)
    #pragma unroll
    for (int nt = 0; nt < 2; nt++) acc[mt][nt] = z;
  const u16* Ab = SI + ((size_t)e * 1024 + mt0) * DD;
  const u16* Bb = w1T + ((size_t)e * HH + nt0) * DD;
  int row = t >> 2, off = (t & 3) * 16;
  uint4 pa0, pa1, pb0, pb1;
  pa0 = *(const uint4*)(Ab + (size_t)row * DD + off);
  pa1 = *(const uint4*)(Ab + (size_t)row * DD + off + 8);
  pb0 = *(const uint4*)(Bb + (size_t)row * DD + off);
  pb1 = *(const uint4*)(Bb + (size_t)row * DD + off + 8);
  for (int kb = 0; kb < 16; kb++) {
    *(uint4*)&At[row * 72 + off] = pa0;
    *(uint4*)&At[row * 72 + off + 8] = pa1;
    *(uint4*)&Bt[row * 72 + off] = pb0;
    *(uint4*)&Bt[row * 72 + off + 8] = pb1;
    __syncthreads();
    if (kb < 15) {
      int k0 = (kb + 1) * 64;
      pa0 = *(const uint4*)(Ab + (size_t)row * DD + k0 + off);
      pa1 = *(const uint4*)(Ab + (size_t)row * DD + k0 + off + 8);
      pb0 = *(const uint4*)(Bb + (size_t)row * DD + k0 + off);
      pb1 = *(const uint4*)(Bb + (size_t)row * DD + k0 + off + 8);
    }
    #pragma unroll
    for (int kk = 0; kk < 2; kk++) {
      int k = kk * 32 + q * 8;
      bf16x8 a[2], bb[2];
      #pragma unroll
      for (int mt = 0; mt < 2; mt++)
        a[mt] = *(const bf16x8*)&At[(wm + mt * 16 + m16) * 72 + k];
      #pragma unroll
      for (int nt = 0; nt < 2; nt++)
        bb[nt] = *(const bf16x8*)&Bt[(wn + nt * 16 + m16) * 72 + k];
      #pragma unroll
      for (int mt = 0; mt < 2; mt++)
        #pragma unroll
        for (int nt = 0; nt < 2; nt++)
          acc[mt][nt] = MFMA(a[mt], bb[nt], acc[mt][nt]);
    }
    __syncthreads();
  }
  #pragma unroll
  for (int nt = 0; nt < 2; nt++) {
    int h = nt0 + wn + nt * 16 + m16;
    float b1v = b1[e * HH + h];
    #pragma unroll
    for (int mt = 0; mt < 2; mt++)
      #pragma unroll
      for (int i = 0; i < 4; i++) {
        float zz = acc[mt][nt][i] + b1v;
        int bs = mt0 + wm + mt * 16 + q * 4 + i;
        H[((size_t)e * 1024 + bs) * HH + h] =
            f2b(0.5f * zz * (1.0f + erff(zz * 0.70710678118654752f)));
      }
  }
}

// ------- K7b2: SO[e][bs][d] = H @ w2T + b2; tile 64x64, K=256 -------
__global__ __launch_bounds__(256) void k_mlp2(
    const u16* __restrict__ H, const u16* __restrict__ w2T,
    const float* __restrict__ b2, u16* __restrict__ SO) {
  __shared__ u16 At[64 * 72];
  __shared__ u16 Bt[64 * 72];
  int t = threadIdx.x;
  int lane = t & 63, w = t >> 6, q = lane >> 4, m16 = lane & 15;
  int nt0 = blockIdx.x * 64;   // d
  int mt0 = blockIdx.y * 64;   // bs
  int e = blockIdx.z;
  int wm = (w & 1) * 32, wn = (w >> 1) * 32;
  f32x4 z = {0.f, 0.f, 0.f, 0.f};
  f32x4 acc[2][2];
  #pragma unroll
  for (int mt = 0; mt < 2; mt++)
    #pragma unroll
    for (int nt = 0; nt < 2; nt++) acc[mt][nt] = z;
  const u16* Ab = H + ((size_t)e * 1024 + mt0) * HH;
  const u16* Bb = w2T + ((size_t)e * DD + nt0) * HH;
  int row = t >> 2, off = (t & 3) * 16;
  uint4 pa0, pa1, pb0, pb1;
  pa0 = *(const uint4*)(Ab + (size_t)row * HH + off);
  pa1 = *(const uint4*)(Ab + (size_t)row * HH + off + 8);
  pb0 = *(const uint4*)(Bb + (size_t)row * HH + off);
  pb1 = *(const uint4*)(Bb + (size_t)row * HH + off + 8);
  for (int kb = 0; kb < 4; kb++) {
    *(uint4*)&At[row * 72 + off] = pa0;
    *(uint4*)&At[row * 72 + off + 8] = pa1;
    *(uint4*)&Bt[row * 72 + off] = pb0;
    *(uint4*)&Bt[row * 72 + off + 8] = pb1;
    __syncthreads();
    if (kb < 3) {
      int k0 = (kb + 1) * 64;
      pa0 = *(const uint4*)(Ab + (size_t)row * HH + k0 + off);
      pa1 = *(const uint4*)(Ab + (size_t)row * HH + k0 + off + 8);
      pb0 = *(const uint4*)(Bb + (size_t)row * HH + k0 + off);
      pb1 = *(const uint4*)(Bb + (size_t)row * HH + k0 + off + 8);
    }
    #pragma unroll
    for (int kk = 0; kk < 2; kk++) {
      int k = kk * 32 + q * 8;
      bf16x8 a[2], bb[2];
      #pragma unroll
      for (int mt = 0; mt < 2; mt++)
        a[mt] = *(const bf16x8*)&At[(wm + mt * 16 + m16) * 72 + k];
      #pragma unroll
      for (int nt = 0; nt < 2; nt++)
        bb[nt] = *(const bf16x8*)&Bt[(wn + nt * 16 + m16) * 72 + k];
      #pragma unroll
      for (int mt = 0; mt < 2; mt++)
        #pragma unroll
        for (int nt = 0; nt < 2; nt++)
          acc[mt][nt] = MFMA(a[mt], bb[nt], acc[mt][nt]);
    }
    __syncthreads();
  }
  // epilogue: acc + b2 -> At (reused as [64 bs][72 d] bf16), then coalesced
  #pragma unroll
  for (int nt = 0; nt < 2; nt++) {
    int dl = wn + nt * 16 + m16;
    float b2v = b2[e * DD + nt0 + dl];
    #pragma unroll
    for (int mt = 0; mt < 2; mt++)
      #pragma unroll
      for (int i = 0; i < 4; i++) {
        int bl = wm + mt * 16 + q * 4 + i;
        At[bl * 72 + dl] = f2b(acc[mt][nt][i] + b2v);
      }
  }
  __syncthreads();
  u16* dst = SO + ((size_t)e * 1024 + mt0 + row) * DD + nt0 + off;
  *(uint4*)dst = *(const uint4*)&At[row * 72 + off];
  *(uint4*)(dst + 8) = *(const uint4*)&At[row * 72 + off + 8];
}

// ------- K8: output GEMM (MFMA); combine weights precomputed by k_comb -------
__global__ __launch_bounds__(256) void k_out_mfma(
    const u16* __restrict__ slot_out, const float* __restrict__ logitsT,
    float* __restrict__ out) {
  __shared__ u16 comb[32 * 264];  // [32 tokens][256 es] K-major bf16
  __shared__ u16 sot[64 * 264];   // [64 d][256 es] K-major bf16
  int t = threadIdx.x;
  int lane = t & 63, w = t >> 6, q = lane >> 4, m16 = lane & 15;
  int id = blockIdx.x;
  int b = (id & 7) * 8 + ((id >> 3) & 7);
  int dc = id >> 6;  // 16 strips of 64 d
  // ---- stage SO^T tile once: sot[d][es] from slot_out[e][b*16+s][d] ----
  {
    int es2 = (t & 127) * 2, dh = t >> 7;
    const u16* s0 = slot_out +
        ((size_t)((es2 >> 4) * 1024 + b * 16 + (es2 & 15))) * DD +
        dc * 64 + dh * 32;
    const u16* s1 = s0 + DD;  // es2+1: same e, s+1 (es2 even)
    #pragma unroll
    for (int k2 = 0; k2 < 8; k2++) {
      ushort4 r0 = *(const ushort4*)(s0 + k2 * 4);
      ushort4 r1 = *(const ushort4*)(s1 + k2 * 4);
      int dl = dh * 32 + k2 * 4;
      *(u32*)&sot[(dl + 0) * 264 + es2] = (u32)r0.x | ((u32)r1.x << 16);
      *(u32*)&sot[(dl + 1) * 264 + es2] = (u32)r0.y | ((u32)r1.y << 16);
      *(u32*)&sot[(dl + 2) * 264 + es2] = (u32)r0.z | ((u32)r1.z << 16);
      *(u32*)&sot[(dl + 3) * 264 + es2] = (u32)r0.w | ((u32)r1.w << 16);
    }
  }
  for (int nch = 0; nch < 8; nch++) {
    int n0 = nch * 32;
    __syncthreads();  // sot staged (iter 0) / prev GEMM done with comb (iter>0)
    // ---- load precomputed combine weights (fp32, L2-hot) -> bf16 LDS ----
    {
      int j = t & 31, ch = t >> 5;
      const float* base = logitsT + (size_t)(ch * 32) * BN + b * 256 + n0 + j;
      float lv[32];
      #pragma unroll
      for (int i = 0; i < 32; i++) lv[i] = base[(size_t)i * BN];
      #pragma unroll
      for (int i2 = 0; i2 < 8; i2++) {
        uint2 pk;
        pk.x = (u32)f2b(lv[i2 * 4]) | ((u32)f2b(lv[i2 * 4 + 1]) << 16);
        pk.y = (u32)f2b(lv[i2 * 4 + 2]) | ((u32)f2b(lv[i2 * 4 + 3]) << 16);
        *(uint2*)&comb[j * 264 + ch * 32 + i2 * 4] = pk;
      }
    }
    __syncthreads();
    // ---- GEMM: out[32 n][64 d] = comb @ sot^T over K=256 es ----
    f32x4 aA = {0.f, 0.f, 0.f, 0.f}, aB = {0.f, 0.f, 0.f, 0.f};
    #pragma unroll
    for (int ks = 0; ks < 8; ks++) {
      bf16x8 bb = *(const bf16x8*)&sot[(w * 16 + m16) * 264 + ks * 32 + q * 8];
      bf16x8 a0 = *(const bf16x8*)&comb[m16 * 264 + ks * 32 + q * 8];
      bf16x8 a1 = *(const bf16x8*)&comb[(16 + m16) * 264 + ks * 32 + q * 8];
      aA = MFMA(a0, bb, aA);
      aB = MFMA(a1, bb, aB);
    }
    int d = dc * 64 + w * 16 + m16;
    #pragma unroll
    for (int i = 0; i < 4; i++) {
      out[((size_t)b * NN + n0 + q * 4 + i) * DD + d] = aA[i];
      out[((size_t)b * NN + n0 + 16 + q * 4 + i) * DD + d] = aB[i];
    }
  }
}

extern "C" void kernel_launch(void* const* d_in, const int* in_sizes, int n_in,
                              void* d_out, int out_size, void* d_ws, size_t ws_size,
                              hipStream_t stream) {
  const float* x     = (const float*)d_in[0];
  const float* gamma = (const float*)d_in[1];
  const float* beta  = (const float*)d_in[2];
  const float* mu    = (const float*)d_in[3];
  const float* scale = (const float*)d_in[4];
  const float* w1    = (const float*)d_in[5];
  const float* b1    = (const float*)d_in[6];
  const float* w2    = (const float*)d_in[7];
  const float* b2    = (const float*)d_in[8];
  float* out = (float*)d_out;

  // ws: SI/SO bf16 [16e][1024 bs][1024 d] @0 (33,554,432; SI then SO overwrite)
  //     logitsT fp32 [256 es][16384 bn] @33,554,432 (16,777,216)
  //     mean @50,331,648 | rstd @50,397,184 | fct @50,462,720 (64 KB each)
  //     rmun @50,528,256 | c3 @50,529,280 | c4 @50,530,304 (1 KB each)
  const size_t WS_NEED = 50531328;
  if (ws_size < WS_NEED) return;
  char* ws = (char*)d_ws;
  u16*   sislot  = (u16*)(ws);          // SI, later SO
  float* logitsT = (float*)(ws + 33554432);
  float* mean_   = (float*)(ws + 50331648);
  float* rstd_   = (float*)(ws + 50397184);
  float* fct_    = (float*)(ws + 50462720);
  float* rmun    = (float*)(ws + 50528256);
  float* c3      = (float*)(ws + 50529280);
  float* c4      = (float*)(ws + 50530304);

  // d_out as scratch until k_out_mfma overwrites with final fp32 out:
  //   xT bf16 [1024][16384] @0 (33,554,432)
  //   w1T @33,554,432 (8,388,608) | w2T @41,943,040 (8,388,608)
  //   dispW bf16 [64b][256es][256n] @50,331,648 (8,388,608)
  //   H region @58,720,256 (8,388,608): holds muT (@58,720,256, 524,288) and
  //   c1g (@59,244,544, 65,536) until k_slotin done; then k_mlp1 writes H here.
  char* sc = (char*)d_out;
  u16* xT    = (u16*)(sc);
  u16* w1T   = (u16*)(sc + 33554432);
  u16* w2T   = (u16*)(sc + 41943040);
  u16* dispW = (u16*)(sc + 50331648);
  u16* muT   = (u16*)(sc + 58720256);
  float* c1g = (float*)(sc + 59244544);
  u16* Hbuf  = (u16*)(sc + 58720256);

  k_stats<<<BN, 256, 0, stream>>>(x, gamma, beta, scale, mean_, rstd_, fct_);
  k_rmun<<<ES, 256, 0, stream>>>(mu, gamma, beta, rmun, c3, c4);
  k_mut<<<16, 256, 0, stream>>>(mu, gamma, rmun, muT);
  k_xt<<<dim3(BN / 64, 4), 256, 0, stream>>>(x, xT);
  k_tr<<<dim3(64, EE), 256, 0, stream>>>(w1, w1T, DD, HH);  // w1T[e][h][d]
  k_tr<<<dim3(64, EE), 256, 0, stream>>>(w2, w2T, HH, DD);  // w2T[e][d][h]
  k_logits_mfma<<<dim3(BN / 64, 4), 256, 0, stream>>>(x, muT, mean_, rstd_,
                                                      fct_, c3, c4, logitsT);
  k_disp<<<dim3(EE, BB), 256, 0, stream>>>(logitsT, mean_, rstd_, dispW, c1g);
  k_comb<<<dim3(4, BB), 256, 0, stream>>>(logitsT);
  k_slotin<<<dim3(8, BB), 256, 0, stream>>>(xT, dispW, c1g, gamma, beta, sislot);
  k_mlp1<<<dim3(4, 16, EE), 256, 0, stream>>>(sislot, w1T, b1, Hbuf);
  k_mlp2<<<dim3(16, 16, EE), 256, 0, stream>>>(Hbuf, w2T, b2, sislot);
  k_out_mfma<<<dim3(1024), 256, 0, stream>>>(sislot, logitsT, out);
}

// Round 14
// 332.642 us; speedup vs baseline: 1.1852x; 1.0228x over previous
//
#include <hip/hip_runtime.h>

#define DD 1024
#define NN 256
#define BB 64
#define EE 16
#define SS 16
#define HH 256
#define ES 256
#define BN 16384

typedef unsigned short u16;
typedef unsigned int u32;
typedef __attribute__((ext_vector_type(8))) short bf16x8;
typedef __attribute__((ext_vector_type(4))) float f32x4;

#define MFMA(a, b, c) __builtin_amdgcn_mfma_f32_16x16x32_bf16(a, b, c, 0, 0, 0)

__device__ __forceinline__ u16 f2b(float f) {
  union { float f; u32 i; } c; c.f = f;
  u32 i = c.i;
  u32 r = (i + 0x7FFFu + ((i >> 16) & 1u)) >> 16;
  return (u16)r;
}

// block = 256 threads (4 waves). Sums v across the block, result broadcast.
__device__ __forceinline__ float bredsum(float v, float* red) {
  #pragma unroll
  for (int o = 32; o > 0; o >>= 1) v += __shfl_down(v, o, 64);
  __syncthreads();
  if ((threadIdx.x & 63) == 0) red[threadIdx.x >> 6] = v;
  __syncthreads();
  return red[0] + red[1] + red[2] + red[3];
}

// ---------------- K1: per-token LN stats + l2 factor ----------------
__global__ __launch_bounds__(256) void k_stats(
    const float* __restrict__ x, const float* __restrict__ gamma,
    const float* __restrict__ beta, const float* __restrict__ scale,
    float* __restrict__ mean_, float* __restrict__ rstd_,
    float* __restrict__ fct_) {
  __shared__ float red[4];
  int bn = blockIdx.x, t = threadIdx.x;
  float4 u = ((const float4*)(x + (size_t)bn * DD))[t];
  float s = u.x + u.y + u.z + u.w;
  float ss = u.x * u.x + u.y * u.y + u.z * u.z + u.w * u.w;
  s = bredsum(s, red);
  ss = bredsum(ss, red);
  float mean = s * (1.0f / DD);
  float var = ss * (1.0f / DD) - mean * mean;
  float rstd = rsqrtf(var + 1e-5f);
  float4 g = ((const float4*)gamma)[t];
  float4 be = ((const float4*)beta)[t];
  float x0 = (u.x - mean) * rstd * g.x + be.x;
  float x1 = (u.y - mean) * rstd * g.y + be.y;
  float x2 = (u.z - mean) * rstd * g.z + be.z;
  float x3 = (u.w - mean) * rstd * g.w + be.w;
  float s2 = x0 * x0 + x1 * x1 + x2 * x2 + x3 * x3;
  s2 = bredsum(s2, red);
  float f = scale[0] / fmaxf(sqrtf(s2), 1e-12f);
  if (t == 0) { mean_[bn] = mean; rstd_[bn] = rstd; fct_[bn] = f; }
}

// ------- K2: rmun/c3/c4 + fused muT write (was separate k_mut) -------
// muT[es][d] = mu[d][es]*rmun[es]*gamma[d] (bf16, K-major); block already
// holds all mu[:,es] and gamma values, so write after the reduction.
__global__ __launch_bounds__(256) void k_rmun(
    const float* __restrict__ mu, const float* __restrict__ gamma,
    const float* __restrict__ beta, float* __restrict__ rmun,
    float* __restrict__ c3, float* __restrict__ c4, u16* __restrict__ muT) {
  __shared__ float red[4];
  int es = blockIdx.x, t = threadIdx.x;
  float v[4], g[4];
  float ss = 0.f, s3 = 0.f, s4 = 0.f;
  #pragma unroll
  for (int j = 0; j < 4; j++) {
    int d = t + j * 256;
    v[j] = mu[(size_t)d * ES + es];
    g[j] = gamma[d];
    ss += v[j] * v[j];
    s3 += g[j] * v[j];
    s4 += beta[d] * v[j];
  }
  ss = bredsum(ss, red);
  s3 = bredsum(s3, red);
  s4 = bredsum(s4, red);
  float r = 1.0f / fmaxf(sqrtf(ss), 1e-12f);
  if (t == 0) {
    rmun[es] = r;
    c3[es] = s3 * r;
    c4[es] = s4 * r;
  }
  #pragma unroll
  for (int j = 0; j < 4; j++)
    muT[(size_t)es * DD + t + j * 256] = f2b(v[j] * r * g[j]);
}

// ------- K4: xT[d][bn] = bf16(x[bn][d]) — raw-x transpose -------
// cch split across blockIdx.y: grid (256,4)=1024 blocks (4/CU, 16 waves/CU).
__global__ __launch_bounds__(256) void k_xt(
    const float* __restrict__ x, u16* __restrict__ xT) {
  __shared__ u16 L[256 * 70];
  int t = threadIdx.x;
  int bn0 = blockIdx.x * 64;
  int cch = blockIdx.y;
  for (int r = 0; r < 64; r++)
    L[t * 70 + r] = f2b(x[(size_t)(bn0 + r) * DD + cch * 256 + t]);
  __syncthreads();
  u32 buf[32];
  #pragma unroll
  for (int k2 = 0; k2 < 32; k2++)
    buf[k2] = *(const u32*)&L[t * 70 + k2 * 2];
  u16* dst = xT + (size_t)(cch * 256 + t) * BN + bn0;
  #pragma unroll
  for (int k4 = 0; k4 < 8; k4++) {
    uint4 o;
    o.x = buf[k4 * 4]; o.y = buf[k4 * 4 + 1];
    o.z = buf[k4 * 4 + 2]; o.w = buf[k4 * 4 + 3];
    *(uint4*)(dst + k4 * 8) = o;
  }
}

// ------- K5: both expert-weight transposes in ONE launch (z: 0=w1, 1=w2) ----
// src[e][R][C] fp32 -> dst[e][C][R] bf16; tR*(C/64) = 64 blocks.x either way.
__global__ __launch_bounds__(256) void k_tr2(
    const float* __restrict__ w1, u16* __restrict__ w1T,
    const float* __restrict__ w2, u16* __restrict__ w2T) {
  __shared__ u16 T[64 * 70];
  int t = threadIdx.x;
  int e = blockIdx.y;
  const float* src; u16* dst; int R, C;
  if (blockIdx.z == 0) { src = w1; dst = w1T; R = DD; C = HH; }
  else                 { src = w2; dst = w2T; R = HH; C = DD; }
  int tR = R >> 6;
  int r0 = (blockIdx.x % tR) * 64;
  int c0 = (blockIdx.x / tR) * 64;
  #pragma unroll
  for (int i = 0; i < 16; i++) {
    int r = r0 + i * 4 + (t >> 6);
    int c = t & 63;
    T[c * 70 + i * 4 + (t >> 6)] = f2b(src[((size_t)e * R + r) * C + c0 + c]);
  }
  __syncthreads();
  int cl = t >> 2, rsg = (t & 3) * 16;
  u32 buf[8];
  #pragma unroll
  for (int k2 = 0; k2 < 8; k2++)
    buf[k2] = *(const u32*)&T[cl * 70 + rsg + k2 * 2];
  u16* dp = dst + ((size_t)e * C + c0 + cl) * R + r0 + rsg;
  uint4 o0, o1;
  o0.x = buf[0]; o0.y = buf[1]; o0.z = buf[2]; o0.w = buf[3];
  o1.x = buf[4]; o1.y = buf[5]; o1.z = buf[6]; o1.w = buf[7];
  *(uint4*)dp = o0;
  *(uint4*)(dp + 8) = o1;
}

// ------- K6: logitsT[es][bn] via MFMA: fct*(rs*(X.MU') - rs*mn*c3 + c4) -------
// 64-token strip x 64-es chunk (blockIdx.y): grid (256,4)=1024 blocks (4/CU,
// 16 waves/CU). Wave owns 16 es -> 1 muT a-load reused over 4 bb MFMAs.
__global__ __launch_bounds__(256) void k_logits_mfma(
    const float* __restrict__ x, const u16* __restrict__ muT,
    const float* __restrict__ mean_, const float* __restrict__ rstd_,
    const float* __restrict__ fct_, const float* __restrict__ c3,
    const float* __restrict__ c4, float* __restrict__ logitsT) {
  __shared__ u16 xb[64 * 136];  // [64 bn][128 k] bf16, K-major, pad 8
  int t = threadIdx.x;
  int lane = t & 63, w = t >> 6, q = lane >> 4, m16 = lane & 15;
  int bn0 = blockIdx.x * 64;
  int es0 = blockIdx.y * 64 + w * 16;
  f32x4 z = {0.f, 0.f, 0.f, 0.f};
  f32x4 acc[4];
  #pragma unroll
  for (int nt = 0; nt < 4; nt++) acc[nt] = z;
  int sr = t >> 5, cc = (t & 31) * 4;
  float4 pf[8];
  #pragma unroll
  for (int it = 0; it < 8; it++)
    pf[it] = *(const float4*)(x + (size_t)(bn0 + sr + it * 8) * DD + cc);
  for (int kb = 0; kb < 8; kb++) {
    __syncthreads();
    #pragma unroll
    for (int it = 0; it < 8; it++) {
      int row = sr + it * 8;
      uint2 pk;
      pk.x = (u32)f2b(pf[it].x) | ((u32)f2b(pf[it].y) << 16);
      pk.y = (u32)f2b(pf[it].z) | ((u32)f2b(pf[it].w) << 16);
      *(uint2*)&xb[row * 136 + cc] = pk;
    }
    __syncthreads();
    if (kb < 7) {
      #pragma unroll
      for (int it = 0; it < 8; it++)
        pf[it] = *(const float4*)(x + (size_t)(bn0 + sr + it * 8) * DD +
                                  (kb + 1) * 128 + cc);
    }
    #pragma unroll
    for (int ks = 0; ks < 4; ks++) {
      int k = ks * 32 + q * 8;
      bf16x8 a = *(const bf16x8*)(muT + (size_t)(es0 + m16) * DD +
                                  kb * 128 + k);
      #pragma unroll
      for (int nt = 0; nt < 4; nt++) {
        bf16x8 bb = *(const bf16x8*)&xb[(nt * 16 + m16) * 136 + k];
        acc[nt] = MFMA(a, bb, acc[nt]);
      }
    }
  }
  #pragma unroll
  for (int nt = 0; nt < 4; nt++) {
    int bn = bn0 + nt * 16 + m16;
    float fv = fct_[bn], rv = rstd_[bn], mv = mean_[bn];
    #pragma unroll
    for (int i = 0; i < 4; i++) {
      int es = es0 + q * 4 + i;
      float val = fv * (rv * acc[nt][i] - rv * mv * c3[es] + c4[es]);
      logitsT[(size_t)es * BN + bn] = val;
    }
  }
}

// ------- K6b: dispatch softmax -> dispW[b][es][n] bf16 (K-major n) + c1g[b][es]
__global__ __launch_bounds__(256) void k_disp(
    const float* __restrict__ logitsT, const float* __restrict__ mean_,
    const float* __restrict__ rstd_, u16* __restrict__ dispW,
    float* __restrict__ c1g) {
  int t = threadIdx.x;
  int e = blockIdx.x, b = blockIdx.y;
  int s = t >> 4, c = t & 15;
  const float* lrow = logitsT + (size_t)(e * 16 + s) * BN + b * 256 + c * 16;
  float lv[16];
  #pragma unroll
  for (int i2 = 0; i2 < 4; i2++) {
    float4 f = *(const float4*)(lrow + i2 * 4);
    lv[i2 * 4 + 0] = f.x; lv[i2 * 4 + 1] = f.y;
    lv[i2 * 4 + 2] = f.z; lv[i2 * 4 + 3] = f.w;
  }
  float mx = -1e30f;
  #pragma unroll
  for (int i = 0; i < 16; i++) mx = fmaxf(mx, lv[i]);
  #pragma unroll
  for (int o = 1; o < 16; o <<= 1) mx = fmaxf(mx, __shfl_xor(mx, o, 64));
  float sum = 0.f;
  #pragma unroll
  for (int i = 0; i < 16; i++) { lv[i] = __expf(lv[i] - mx); sum += lv[i]; }
  #pragma unroll
  for (int o = 1; o < 16; o <<= 1) sum += __shfl_xor(sum, o, 64);
  float inv = 1.0f / sum;
  float c1p = 0.f;
  u16 wp[16];
  #pragma unroll
  for (int i = 0; i < 16; i++) {
    int n = c * 16 + i;
    float wv = lv[i] * inv * rstd_[b * 256 + n];
    c1p += wv * mean_[b * 256 + n];
    wp[i] = f2b(wv);
  }
  #pragma unroll
  for (int o = 1; o < 16; o <<= 1) c1p += __shfl_xor(c1p, o, 64);
  if (c == 0) c1g[(b << 8) + e * 16 + s] = c1p;
  u16* drow = dispW + ((size_t)(b * 256 + e * 16 + s)) * 256 + c * 16;
  #pragma unroll
  for (int i2 = 0; i2 < 4; i2++) {
    uint2 pk;
    pk.x = (u32)wp[i2 * 4] | ((u32)wp[i2 * 4 + 1] << 16);
    pk.y = (u32)wp[i2 * 4 + 2] | ((u32)wp[i2 * 4 + 3] << 16);
    *(uint2*)(drow + i2 * 4) = pk;
  }
}

// ------- K6c: in-place combine-softmax normalization of logitsT -------
// Each block writes only its own 64 token columns -> race-free in place.
// (Round-13 lesson: k_out may read NOTHING from d_out scratch — it
// progressively overwrites all of d_out — so combine weights stay in ws.)
__global__ __launch_bounds__(256) void k_comb(float* __restrict__ logitsT) {
  __shared__ float red[4][64];
  int t = threadIdx.x;
  int l = t & 63, g = t >> 6;
  int bn = blockIdx.y * 256 + blockIdx.x * 64 + l;
  float* base = logitsT + (size_t)(g * 64) * BN + bn;
  float ev[64];
  float sum = 0.f;
  #pragma unroll
  for (int i = 0; i < 64; i++) {
    float e = __expf(base[(size_t)i * BN]);
    ev[i] = e;
    sum += e;
  }
  red[g][l] = sum;
  __syncthreads();
  float inv = 1.0f / (red[0][l] + red[1][l] + red[2][l] + red[3][l]);
  #pragma unroll
  for (int i = 0; i < 64; i++)
    base[(size_t)i * BN] = ev[i] * inv;
}

// ------- K7a: SI[e][b*16+s][d] = gamma*(dispW[b] @ xT - c1) + beta  (M=256) ----
__global__ __launch_bounds__(256) void k_slotin(
    const u16* __restrict__ xT, const u16* __restrict__ dispW,
    const float* __restrict__ c1g, const float* __restrict__ gamma,
    const float* __restrict__ beta, u16* __restrict__ SI) {
  __shared__ u16 xb[128 * 264];  // [128 d][256 n] pad->264 (2-way bank = free)
  int t = threadIdx.x;
  int lane = t & 63, w = t >> 6, q = lane >> 4, m16 = lane & 15;
  int d0 = blockIdx.x * 128, b = blockIdx.y;
  #pragma unroll
  for (int it = 0; it < 16; it++) {
    int c = it * 256 + t;
    int row = c >> 5, off = (c & 31) * 8;
    uint4 v = *(const uint4*)(xT + (size_t)(d0 + row) * BN + b * 256 + off);
    *(uint4*)&xb[row * 264 + off] = v;
  }
  __syncthreads();
  f32x4 z = {0.f, 0.f, 0.f, 0.f};
  f32x4 acc[4][8];
  #pragma unroll
  for (int mt = 0; mt < 4; mt++)
    #pragma unroll
    for (int nt = 0; nt < 8; nt++) acc[mt][nt] = z;
  int es0 = w * 64;
  for (int ks = 0; ks < 8; ks++) {
    int k = ks * 32 + q * 8;
    bf16x8 a[4];
    #pragma unroll
    for (int mt = 0; mt < 4; mt++)
      a[mt] = *(const bf16x8*)(dispW +
               ((size_t)(b * 256 + es0 + mt * 16 + m16)) * 256 + k);
    #pragma unroll
    for (int nt = 0; nt < 8; nt++) {
      bf16x8 bb = *(const bf16x8*)&xb[(nt * 16 + m16) * 264 + k];
      #pragma unroll
      for (int mt = 0; mt < 4; mt++) acc[mt][nt] = MFMA(a[mt], bb, acc[mt][nt]);
    }
  }
  float gv[8], bev[8];
  #pragma unroll
  for (int nt = 0; nt < 8; nt++) {
    int d = d0 + nt * 16 + m16;
    gv[nt] = gamma[d]; bev[nt] = beta[d];
  }
  #pragma unroll
  for (int mt = 0; mt < 4; mt++) {
    float c1[4];
    #pragma unroll
    for (int i = 0; i < 4; i++)
      c1[i] = c1g[(b << 8) + es0 + mt * 16 + q * 4 + i];
    #pragma unroll
    for (int nt = 0; nt < 8; nt++)
      #pragma unroll
      for (int i = 0; i < 4; i++)
        SI[((size_t)(w * 4 + mt) * 1024 + b * 16 + q * 4 + i) * DD + d0 +
           nt * 16 + m16] = f2b(gv[nt] * (acc[mt][nt][i] - c1[i]) + bev[nt]);
  }
}

// ------- K7b1: H[e][bs][h] = gelu(SI @ w1T + b1); tile 64x64, K=1024 -------
__global__ __launch_bounds__(256) void k_mlp1(
    const u16* __restrict__ SI, const u16* __restrict__ w1T,
    const float* __restrict__ b1, u16* __restrict__ H) {
  __shared__ u16 At[64 * 72];
  __shared__ u16 Bt[64 * 72];
  int t = threadIdx.x;
  int lane = t & 63, w = t >> 6, q = lane >> 4, m16 = lane & 15;
  int nt0 = blockIdx.x * 64;   // h
  int mt0 = blockIdx.y * 64;   // bs
  int e = blockIdx.z;
  int wm = (w & 1) * 32, wn = (w >> 1) * 32;
  f32x4 z = {0.f, 0.f, 0.f, 0.f};
  f32x4 acc[2][2];
  #pragma unroll
  for (int mt = 0; mt < 2; mt++)
    #pragma unroll
    for (int nt = 0; nt < 2; nt++) acc[mt][nt] = z;
  const u16* Ab = SI + ((size_t)e * 1024 + mt0) * DD;
  const u16* Bb = w1T + ((size_t)e * HH + nt0) * DD;
  int row = t >> 2, off = (t & 3) * 16;
  uint4 pa0, pa1, pb0, pb1;
  pa0 = *(const uint4*)(Ab + (size_t)row * DD + off);
  pa1 = *(const uint4*)(Ab + (size_t)row * DD + off + 8);
  pb0 = *(const uint4*)(Bb + (size_t)row * DD + off);
  pb1 = *(const uint4*)(Bb + (size_t)row * DD + off + 8);
  for (int kb = 0; kb < 16; kb++) {
    *(uint4*)&At[row * 72 + off] = pa0;
    *(uint4*)&At[row * 72 + off + 8] = pa1;
    *(uint4*)&Bt[row * 72 + off] = pb0;
    *(uint4*)&Bt[row * 72 + off + 8] = pb1;
    __syncthreads();
    if (kb < 15) {
      int k0 = (kb + 1) * 64;
      pa0 = *(const uint4*)(Ab + (size_t)row * DD + k0 + off);
      pa1 = *(const uint4*)(Ab + (size_t)row * DD + k0 + off + 8);
      pb0 = *(const uint4*)(Bb + (size_t)row * DD + k0 + off);
      pb1 = *(const uint4*)(Bb + (size_t)row * DD + k0 + off + 8);
    }
    #pragma unroll
    for (int kk = 0; kk < 2; kk++) {
      int k = kk * 32 + q * 8;
      bf16x8 a[2], bb[2];
      #pragma unroll
      for (int mt = 0; mt < 2; mt++)
        a[mt] = *(const bf16x8*)&At[(wm + mt * 16 + m16) * 72 + k];
      #pragma unroll
      for (int nt = 0; nt < 2; nt++)
        bb[nt] = *(const bf16x8*)&Bt[(wn + nt * 16 + m16) * 72 + k];
      #pragma unroll
      for (int mt = 0; mt < 2; mt++)
        #pragma unroll
        for (int nt = 0; nt < 2; nt++)
          acc[mt][nt] = MFMA(a[mt], bb[nt], acc[mt][nt]);
    }
    __syncthreads();
  }
  #pragma unroll
  for (int nt = 0; nt < 2; nt++) {
    int h = nt0 + wn + nt * 16 + m16;
    float b1v = b1[e * HH + h];
    #pragma unroll
    for (int mt = 0; mt < 2; mt++)
      #pragma unroll
      for (int i = 0; i < 4; i++) {
        float zz = acc[mt][nt][i] + b1v;
        int bs = mt0 + wm + mt * 16 + q * 4 + i;
        H[((size_t)e * 1024 + bs) * HH + h] =
            f2b(0.5f * zz * (1.0f + erff(zz * 0.70710678118654752f)));
      }
  }
}

// ------- K7b2: SO[e][bs][d] = H @ w2T + b2; tile 64x64, K=256 -------
__global__ __launch_bounds__(256) void k_mlp2(
    const u16* __restrict__ H, const u16* __restrict__ w2T,
    const float* __restrict__ b2, u16* __restrict__ SO) {
  __shared__ u16 At[64 * 72];
  __shared__ u16 Bt[64 * 72];
  int t = threadIdx.x;
  int lane = t & 63, w = t >> 6, q = lane >> 4, m16 = lane & 15;
  int nt0 = blockIdx.x * 64;   // d
  int mt0 = blockIdx.y * 64;   // bs
  int e = blockIdx.z;
  int wm = (w & 1) * 32, wn = (w >> 1) * 32;
  f32x4 z = {0.f, 0.f, 0.f, 0.f};
  f32x4 acc[2][2];
  #pragma unroll
  for (int mt = 0; mt < 2; mt++)
    #pragma unroll
    for (int nt = 0; nt < 2; nt++) acc[mt][nt] = z;
  const u16* Ab = H + ((size_t)e * 1024 + mt0) * HH;
  const u16* Bb = w2T + ((size_t)e * DD + nt0) * HH;
  int row = t >> 2, off = (t & 3) * 16;
  uint4 pa0, pa1, pb0, pb1;
  pa0 = *(const uint4*)(Ab + (size_t)row * HH + off);
  pa1 = *(const uint4*)(Ab + (size_t)row * HH + off + 8);
  pb0 = *(const uint4*)(Bb + (size_t)row * HH + off);
  pb1 = *(const uint4*)(Bb + (size_t)row * HH + off + 8);
  for (int kb = 0; kb < 4; kb++) {
    *(uint4*)&At[row * 72 + off] = pa0;
    *(uint4*)&At[row * 72 + off + 8] = pa1;
    *(uint4*)&Bt[row * 72 + off] = pb0;
    *(uint4*)&Bt[row * 72 + off + 8] = pb1;
    __syncthreads();
    if (kb < 3) {
      int k0 = (kb + 1) * 64;
      pa0 = *(const uint4*)(Ab + (size_t)row * HH + k0 + off);
      pa1 = *(const uint4*)(Ab + (size_t)row * HH + k0 + off + 8);
      pb0 = *(const uint4*)(Bb + (size_t)row * HH + k0 + off);
      pb1 = *(const uint4*)(Bb + (size_t)row * HH + k0 + off + 8);
    }
    #pragma unroll
    for (int kk = 0; kk < 2; kk++) {
      int k = kk * 32 + q * 8;
      bf16x8 a[2], bb[2];
      #pragma unroll
      for (int mt = 0; mt < 2; mt++)
        a[mt] = *(const bf16x8*)&At[(wm + mt * 16 + m16) * 72 + k];
      #pragma unroll
      for (int nt = 0; nt < 2; nt++)
        bb[nt] = *(const bf16x8*)&Bt[(wn + nt * 16 + m16) * 72 + k];
      #pragma unroll
      for (int mt = 0; mt < 2; mt++)
        #pragma unroll
        for (int nt = 0; nt < 2; nt++)
          acc[mt][nt] = MFMA(a[mt], bb[nt], acc[mt][nt]);
    }
    __syncthreads();
  }
  // epilogue: acc + b2 -> At (reused as [64 bs][72 d] bf16), then coalesced
  #pragma unroll
  for (int nt = 0; nt < 2; nt++) {
    int dl = wn + nt * 16 + m16;
    float b2v = b2[e * DD + nt0 + dl];
    #pragma unroll
    for (int mt = 0; mt < 2; mt++)
      #pragma unroll
      for (int i = 0; i < 4; i++) {
        int bl = wm + mt * 16 + q * 4 + i;
        At[bl * 72 + dl] = f2b(acc[mt][nt][i] + b2v);
      }
  }
  __syncthreads();
  u16* dst = SO + ((size_t)e * 1024 + mt0 + row) * DD + nt0 + off;
  *(uint4*)dst = *(const uint4*)&At[row * 72 + off];
  *(uint4*)(dst + 8) = *(const uint4*)&At[row * 72 + off + 8];
}

// ------- K8: output GEMM (MFMA); combine weights precomputed by k_comb -------
__global__ __launch_bounds__(256) void k_out_mfma(
    const u16* __restrict__ slot_out, const float* __restrict__ logitsT,
    float* __restrict__ out) {
  __shared__ u16 comb[32 * 264];  // [32 tokens][256 es] K-major bf16
  __shared__ u16 sot[64 * 264];   // [64 d][256 es] K-major bf16
  int t = threadIdx.x;
  int lane = t & 63, w = t >> 6, q = lane >> 4, m16 = lane & 15;
  int id = blockIdx.x;
  int b = (id & 7) * 8 + ((id >> 3) & 7);
  int dc = id >> 6;  // 16 strips of 64 d
  // ---- stage SO^T tile once: sot[d][es] from slot_out[e][b*16+s][d] ----
  {
    int es2 = (t & 127) * 2, dh = t >> 7;
    const u16* s0 = slot_out +
        ((size_t)((es2 >> 4) * 1024 + b * 16 + (es2 & 15))) * DD +
        dc * 64 + dh * 32;
    const u16* s1 = s0 + DD;  // es2+1: same e, s+1 (es2 even)
    #pragma unroll
    for (int k2 = 0; k2 < 8; k2++) {
      ushort4 r0 = *(const ushort4*)(s0 + k2 * 4);
      ushort4 r1 = *(const ushort4*)(s1 + k2 * 4);
      int dl = dh * 32 + k2 * 4;
      *(u32*)&sot[(dl + 0) * 264 + es2] = (u32)r0.x | ((u32)r1.x << 16);
      *(u32*)&sot[(dl + 1) * 264 + es2] = (u32)r0.y | ((u32)r1.y << 16);
      *(u32*)&sot[(dl + 2) * 264 + es2] = (u32)r0.z | ((u32)r1.z << 16);
      *(u32*)&sot[(dl + 3) * 264 + es2] = (u32)r0.w | ((u32)r1.w << 16);
    }
  }
  for (int nch = 0; nch < 8; nch++) {
    int n0 = nch * 32;
    __syncthreads();  // sot staged (iter 0) / prev GEMM done with comb (iter>0)
    // ---- load precomputed combine weights (fp32, L2-hot) -> bf16 LDS ----
    {
      int j = t & 31, ch = t >> 5;
      const float* base = logitsT + (size_t)(ch * 32) * BN + b * 256 + n0 + j;
      float lv[32];
      #pragma unroll
      for (int i = 0; i < 32; i++) lv[i] = base[(size_t)i * BN];
      #pragma unroll
      for (int i2 = 0; i2 < 8; i2++) {
        uint2 pk;
        pk.x = (u32)f2b(lv[i2 * 4]) | ((u32)f2b(lv[i2 * 4 + 1]) << 16);
        pk.y = (u32)f2b(lv[i2 * 4 + 2]) | ((u32)f2b(lv[i2 * 4 + 3]) << 16);
        *(uint2*)&comb[j * 264 + ch * 32 + i2 * 4] = pk;
      }
    }
    __syncthreads();
    // ---- GEMM: out[32 n][64 d] = comb @ sot^T over K=256 es ----
    f32x4 aA = {0.f, 0.f, 0.f, 0.f}, aB = {0.f, 0.f, 0.f, 0.f};
    #pragma unroll
    for (int ks = 0; ks < 8; ks++) {
      bf16x8 bb = *(const bf16x8*)&sot[(w * 16 + m16) * 264 + ks * 32 + q * 8];
      bf16x8 a0 = *(const bf16x8*)&comb[m16 * 264 + ks * 32 + q * 8];
      bf16x8 a1 = *(const bf16x8*)&comb[(16 + m16) * 264 + ks * 32 + q * 8];
      aA = MFMA(a0, bb, aA);
      aB = MFMA(a1, bb, aB);
    }
    int d = dc * 64 + w * 16 + m16;
    #pragma unroll
    for (int i = 0; i < 4; i++) {
      out[((size_t)b * NN + n0 + q * 4 + i) * DD + d] = aA[i];
      out[((size_t)b * NN + n0 + 16 + q * 4 + i) * DD + d] = aB[i];
    }
  }
}

extern "C" void kernel_launch(void* const* d_in, const int* in_sizes, int n_in,
                              void* d_out, int out_size, void* d_ws, size_t ws_size,
                              hipStream_t stream) {
  const float* x     = (const float*)d_in[0];
  const float* gamma = (const float*)d_in[1];
  const float* beta  = (const float*)d_in[2];
  const float* mu    = (const float*)d_in[3];
  const float* scale = (const float*)d_in[4];
  const float* w1    = (const float*)d_in[5];
  const float* b1    = (const float*)d_in[6];
  const float* w2    = (const float*)d_in[7];
  const float* b2    = (const float*)d_in[8];
  float* out = (float*)d_out;

  // ws: SI/SO bf16 [16e][1024 bs][1024 d] @0 (33,554,432; SI then SO overwrite)
  //     logitsT fp32 [256 es][16384 bn] @33,554,432 (16,777,216)
  //     mean @50,331,648 | rstd @50,397,184 | fct @50,462,720 (64 KB each)
  //     rmun @50,528,256 | c3 @50,529,280 | c4 @50,530,304 (1 KB each)
  const size_t WS_NEED = 50531328;
  if (ws_size < WS_NEED) return;
  char* ws = (char*)d_ws;
  u16*   sislot  = (u16*)(ws);          // SI, later SO
  float* logitsT = (float*)(ws + 33554432);
  float* mean_   = (float*)(ws + 50331648);
  float* rstd_   = (float*)(ws + 50397184);
  float* fct_    = (float*)(ws + 50462720);
  float* rmun    = (float*)(ws + 50528256);
  float* c3      = (float*)(ws + 50529280);
  float* c4      = (float*)(ws + 50530304);

  // d_out as scratch until k_out_mfma overwrites with final fp32 out.
  // INVARIANT (round-13 lesson): k_out_mfma reads ONLY from ws — it
  // progressively overwrites all of d_out, so nothing it consumes may
  // live here.
  //   xT bf16 [1024][16384] @0 (33,554,432)
  //   w1T @33,554,432 (8,388,608) | w2T @41,943,040 (8,388,608)
  //   dispW bf16 [64b][256es][256n] @50,331,648 (8,388,608)
  //   H region @58,720,256 (8,388,608): holds muT (@58,720,256, 524,288) and
  //   c1g (@59,244,544, 65,536) until k_slotin done; then k_mlp1 writes H here.
  char* sc = (char*)d_out;
  u16* xT    = (u16*)(sc);
  u16* w1T   = (u16*)(sc + 33554432);
  u16* w2T   = (u16*)(sc + 41943040);
  u16* dispW = (u16*)(sc + 50331648);
  u16* muT   = (u16*)(sc + 58720256);
  float* c1g = (float*)(sc + 59244544);
  u16* Hbuf  = (u16*)(sc + 58720256);

  k_stats<<<BN, 256, 0, stream>>>(x, gamma, beta, scale, mean_, rstd_, fct_);
  k_rmun<<<ES, 256, 0, stream>>>(mu, gamma, beta, rmun, c3, c4, muT);
  k_xt<<<dim3(BN / 64, 4), 256, 0, stream>>>(x, xT);
  k_tr2<<<dim3(64, EE, 2), 256, 0, stream>>>(w1, w1T, w2, w2T);
  k_logits_mfma<<<dim3(BN / 64, 4), 256, 0, stream>>>(x, muT, mean_, rstd_,
                                                      fct_, c3, c4, logitsT);
  k_disp<<<dim3(EE, BB), 256, 0, stream>>>(logitsT, mean_, rstd_, dispW, c1g);
  k_comb<<<dim3(4, BB), 256, 0, stream>>>(logitsT);
  k_slotin<<<dim3(8, BB), 256, 0, stream>>>(xT, dispW, c1g, gamma, beta, sislot);
  k_mlp1<<<dim3(4, 16, EE), 256, 0, stream>>>(sislot, w1T, b1, Hbuf);
  k_mlp2<<<dim3(16, 16, EE), 256, 0, stream>>>(Hbuf, w2T, b2, sislot);
  k_out_mfma<<<dim3(1024), 256, 0, stream>>>(sislot, logitsT, out);
}